// Round 6
// baseline (1060.999 us; speedup 1.0000x reference)
//
#include <hip/hip_runtime.h>

typedef unsigned short u16;
typedef unsigned int u32;
typedef __attribute__((ext_vector_type(4))) float f32x4;
typedef __attribute__((ext_vector_type(8))) __bf16 bf16x8;
typedef __attribute__((ext_vector_type(8))) unsigned short u16x8;

#if defined(__has_builtin)
#if __has_builtin(__builtin_amdgcn_global_load_lds)
#define HAS_GLL 1
#endif
#endif

__device__ __forceinline__ u16 f2bf(float f) {
    u32 u = __builtin_bit_cast(u32, f);
    u += 0x7fffu + ((u >> 16) & 1u);
    return (u16)(u >> 16);
}
__device__ __forceinline__ float bf2f(u16 x) {
    return __builtin_bit_cast(float, (u32)x << 16);
}

// ---------------- elementwise conversion ----------------
__global__ __launch_bounds__(256) void cvt_bf16_kernel(const float4* __restrict__ in,
                                                       ushort4* __restrict__ out, int n4) {
    int i = blockIdx.x * 256 + threadIdx.x;
    if (i < n4) {
        float4 v = in[i];
        ushort4 o;
        o.x = f2bf(v.x); o.y = f2bf(v.y); o.z = f2bf(v.z); o.w = f2bf(v.w);
        out[i] = o;
    }
}

// transpose + convert: W [B][K][N] f32 -> Wt [B][N][K] bf16
__global__ __launch_bounds__(256) void transcvt_kernel(const float* __restrict__ W,
                                                       u16* __restrict__ Wt, int K, int N) {
    __shared__ u16 t[32][33];
    int b = blockIdx.z;
    const float* Wb = W + (size_t)b * K * N;
    u16* Wtb = Wt + (size_t)b * K * N;
    int n0 = blockIdx.x * 32, k0 = blockIdx.y * 32;
    int tx = threadIdx.x, ty = threadIdx.y;
#pragma unroll
    for (int j = 0; j < 4; ++j)
        t[ty + j * 8][tx] = f2bf(Wb[(size_t)(k0 + ty + j * 8) * N + n0 + tx]);
    __syncthreads();
#pragma unroll
    for (int j = 0; j < 4; ++j)
        Wtb[(size_t)(n0 + ty + j * 8) * K + k0 + tx] = t[tx][ty + j * 8];
}

// bf16 transpose per z-plane: in [z][R][C] -> out [z][C][R]
__global__ __launch_bounds__(256) void transpose_bf16_kernel(const u16* __restrict__ in,
                                                             u16* __restrict__ out, int R, int C,
                                                             long plane) {
    __shared__ u16 t[64][65];
    const u16* inz = in + (size_t)blockIdx.z * plane;
    u16* outz = out + (size_t)blockIdx.z * plane;
    int r0 = blockIdx.x * 64, c0 = blockIdx.y * 64;
    int tx = threadIdx.x & 15, ty = threadIdx.x >> 4;
#pragma unroll
    for (int j = 0; j < 4; ++j) {
        int r = ty + j * 16;
        ushort4 v = *reinterpret_cast<const ushort4*>(inz + (size_t)(r0 + r) * C + c0 + tx * 4);
        t[r][tx * 4 + 0] = v.x; t[r][tx * 4 + 1] = v.y;
        t[r][tx * 4 + 2] = v.z; t[r][tx * 4 + 3] = v.w;
    }
    __syncthreads();
#pragma unroll
    for (int j = 0; j < 4; ++j) {
        int c = ty + j * 16;
        ushort4 v;
        v.x = t[tx * 4 + 0][c]; v.y = t[tx * 4 + 1][c];
        v.z = t[tx * 4 + 2][c]; v.w = t[tx * 4 + 3][c];
        *reinterpret_cast<ushort4*>(outz + (size_t)(c0 + c) * R + r0 + tx * 4) = v;
    }
}

// ---------------- rd[z][row] = 1 / sum_col expS[z][row][col] ----------------
__global__ __launch_bounds__(256) void rowsum_inv_kernel(const u16* __restrict__ S,
                                                         float* __restrict__ rd, int N,
                                                         long plane, int R) {
    int row = blockIdx.x, z = blockIdx.y;
    const u16* s = S + (size_t)z * plane + (size_t)row * N;
    int tid = threadIdx.x, lane = tid & 63, wid = tid >> 6;
    int cnt = N >> 11;
    __shared__ float red[4];
    float sum = 0.f;
    for (int c = 0; c < cnt; ++c) {
        u16x8 x = *reinterpret_cast<const u16x8*>(s + c * 2048 + tid * 8);
#pragma unroll
        for (int j = 0; j < 8; ++j) sum += bf2f(x[j]);
    }
#pragma unroll
    for (int off = 32; off; off >>= 1) sum += __shfl_down(sum, off);
    if (lane == 0) red[wid] = sum;
    __syncthreads();
    if (tid == 0) rd[(size_t)z * R + row] = 1.f / (red[0] + red[1] + red[2] + red[3]);
}

// ---------------- column-sum partials ----------------
__global__ __launch_bounds__(256) void colsum_part_kernel(const u16* __restrict__ S,
                                                          float* __restrict__ partial,
                                                          int R, int C, int rchunk, int nrb) {
    int col = blockIdx.x * 256 + threadIdx.x;
    int rb = blockIdx.y, z = blockIdx.z;
    const u16* s = S + (size_t)z * R * C + (size_t)rb * rchunk * C + col;
    float sum = 0.f;
    for (int r = 0; r < rchunk; ++r) sum += bf2f(s[(size_t)r * C]);
    partial[((size_t)z * nrb + rb) * C + col] = sum;
}

__global__ __launch_bounds__(256) void colsum_fin_kernel(const float* __restrict__ partial,
                                                         float* __restrict__ rd, int C, int nrb) {
    int col = blockIdx.x * 256 + threadIdx.x;
    int z = blockIdx.y;
    float sum = 0.f;
    for (int rb = 0; rb < nrb; ++rb) sum += partial[((size_t)z * nrb + rb) * C + col];
    rd[(size_t)z * C + col] = 1.f / sum;
}

// ---------------- scale rows of a [R][C] bf16 matrix by rd[(r>>lg)·C + c] ----------------
__global__ __launch_bounds__(256) void scale_rows_kernel(const u16* __restrict__ in,
                                                         u16* __restrict__ out,
                                                         const float* __restrict__ rd,
                                                         int C, int lgdk) {
    int i = (blockIdx.x * 256 + threadIdx.x) * 8;
    int r = i / C, c = i % C;
    const float* rdp = rd + ((size_t)(r >> lgdk)) * C + c;
    u16x8 x = *reinterpret_cast<const u16x8*>(in + i);
    u16x8 o;
#pragma unroll
    for (int j = 0; j < 8; ++j) o[j] = f2bf(bf2f(x[j]) * rdp[j]);
    *reinterpret_cast<u16x8*>(out + i) = o;
}

// ---------------- GEMM: C = A (M,K) * B^T (N,K), row-major, 2-phase prefetch ----------------
// z = hz*ZK + kz: A += hz*sAz + kz*sAz2, B += hz*sBz + kz*sBz2, C elem += z*sCz, bias += z*sBias.
// All EPIs write bf16 via LDS-repacked coalesced epilogue.
enum { E_PROJ = 0, E_EXP, E_EXPM, E_PART };

template <int EPI, int BM>
__global__ __launch_bounds__(256) void gemm_nt(const u16* __restrict__ A, const u16* __restrict__ B,
                                               void* __restrict__ Cv, const float* __restrict__ bias,
                                               int M, int N, int K, int lda, int ldb, int ldc,
                                               float scale, long sAz, long sBz, long sCz,
                                               long sBias, int ZK, long sAz2, long sBz2) {
    constexpr int MF = BM / 32;               // 16x16 frags per wave dim
    constexpr int ITERS = BM * 32 / (256 * 8);
    __shared__ __align__(16) u16 smem[BM * 128];   // staging 2x(A+B) tiles; reused for repack
    const int tid = threadIdx.x;
    const int lane = tid & 63;
    const int wid = tid >> 6;
    const int wr = (wid >> 1) * (BM / 2);
    const int wc = (wid & 1) * (BM / 2);
    const int row0 = blockIdx.x * BM;
    const int col0 = blockIdx.y * BM;
    const long zo = blockIdx.z;
    const long hz = zo / ZK;
    const long kz = zo - hz * ZK;
    const u16* Az = A + hz * sAz + kz * sAz2;
    const u16* Bz = B + hz * sBz + kz * sBz2;
    const long zoff = zo * sCz;
    const float* biasz = bias ? bias + zo * sBias : nullptr;
    f32x4 acc[MF][MF] = {};

    auto As = [&](int buf) { return smem + buf * (BM * 64); };
    auto Bs = [&](int buf) { return smem + buf * (BM * 64) + BM * 32; };

    auto stage = [&](int buf, int k0) {
#pragma unroll
        for (int i = 0; i < ITERS; ++i) {
            int c = tid + i * 256;
            int r = c >> 2;
            int lch = (c & 3) ^ ((r >> 1) & 3);   // logical k-chunk at this physical slot
            const u16* sa = Az + (size_t)(row0 + r) * lda + k0 + lch * 8;
            const u16* sb = Bz + (size_t)(col0 + r) * ldb + k0 + lch * 8;
#ifdef HAS_GLL
            __builtin_amdgcn_global_load_lds(
                (const __attribute__((address_space(1))) void*)sa,
                (__attribute__((address_space(3))) void*)(&As(buf)[c * 8]), 16, 0, 0);
            __builtin_amdgcn_global_load_lds(
                (const __attribute__((address_space(1))) void*)sb,
                (__attribute__((address_space(3))) void*)(&Bs(buf)[c * 8]), 16, 0, 0);
#else
            *reinterpret_cast<uint4*>(&As(buf)[c * 8]) = *reinterpret_cast<const uint4*>(sa);
            *reinterpret_cast<uint4*>(&Bs(buf)[c * 8]) = *reinterpret_cast<const uint4*>(sb);
#endif
        }
    };

    stage(0, 0);
    __syncthreads();
    int cur = 0;
    for (int k0 = 0; k0 < K; k0 += 32) {
        if (k0 + 32 < K) stage(cur ^ 1, k0 + 32);
        bf16x8 af[MF], bv[MF];
#pragma unroll
        for (int m = 0; m < MF; ++m) {
            int rr = wr + m * 16 + (lane & 15);
            int p = (lane >> 4) ^ ((rr >> 1) & 3);
            af[m] = *reinterpret_cast<const bf16x8*>(&As(cur)[rr * 32 + p * 8]);
        }
#pragma unroll
        for (int n = 0; n < MF; ++n) {
            int rr = wc + n * 16 + (lane & 15);
            int p = (lane >> 4) ^ ((rr >> 1) & 3);
            bv[n] = *reinterpret_cast<const bf16x8*>(&Bs(cur)[rr * 32 + p * 8]);
        }
#pragma unroll
        for (int m = 0; m < MF; ++m)
#pragma unroll
            for (int n = 0; n < MF; ++n)
                acc[m][n] = __builtin_amdgcn_mfma_f32_16x16x32_bf16(af[m], bv[n], acc[m][n], 0, 0, 0);
        __syncthreads();          // drains prefetch + protects buffer swap
        cur ^= 1;
    }

    // ---- epilogue: math + LDS repack (swizzled) + coalesced b128 stores ----
    char* lc = reinterpret_cast<char*>(smem);
#pragma unroll
    for (int m = 0; m < MF; ++m) {
#pragma unroll
        for (int n = 0; n < MF; ++n) {
#pragma unroll
            for (int j = 0; j < 4; ++j) {
                int lrow = wr + m * 16 + ((lane >> 4) << 2) + j;
                int lcol = wc + n * 16 + (lane & 15);
                float v = acc[m][n][j];
                if (EPI == E_PROJ) {
                    v += biasz[lcol + col0];
                } else if (EPI == E_EXP || EPI == E_EXPM) {
                    v = __expf(v * scale);
                    if (EPI == E_EXPM && row0 + lrow == col0 + lcol) v = 0.f;
                }
                u32 byte = (u32)((lrow * BM + lcol) * 2) ^ (((lrow >> 2) & 3) << 5);
                *reinterpret_cast<u16*>(lc + byte) = f2bf(v);
            }
        }
    }
    __syncthreads();
    constexpr int CH = BM / 8;            // u16x8 chunks per row
    constexpr int NIT = BM * CH / 256;
    u16* Cp = reinterpret_cast<u16*>(Cv) + zoff;
#pragma unroll
    for (int it = 0; it < NIT; ++it) {
        int idx = it * 256 + tid;
        int rrow = idx / CH, c8 = idx % CH;
        u32 byte = (u32)((rrow * BM + c8 * 8) * 2) ^ (((rrow >> 2) & 3) << 5);
        u16x8 val = *reinterpret_cast<const u16x8*>(lc + byte);
        *reinterpret_cast<u16x8*>(Cp + (size_t)(row0 + rrow) * ldc + col0 + c8 * 8) = val;
    }
}

// ---------------- stage-1 reduce: out[row][h*128+d] = elu(rd_h[row] * sum_kc part[h,kc]) ----------------
__global__ __launch_bounds__(256) void reduce_kc_elu_kernel(const u16* __restrict__ part,
                                                            float* __restrict__ out, int M, int KZ,
                                                            const float* __restrict__ rd) {
    int i = blockIdx.x * 256 + threadIdx.x;   // chunk over M*512/8
    int row = i >> 6;
    int hc = i & 63;
    int h = hc >> 4, c8 = hc & 15;
    long plane = (long)M * 128;
    const u16* p = part + (size_t)(h * KZ) * plane + (size_t)row * 128 + c8 * 8;
    float s[8] = {};
    for (int kc = 0; kc < KZ; ++kc) {
        u16x8 x = *reinterpret_cast<const u16x8*>(p + (size_t)kc * plane);
#pragma unroll
        for (int j = 0; j < 8; ++j) s[j] += bf2f(x[j]);
    }
    float r = rd ? rd[(size_t)h * M + row] : 1.f;
#pragma unroll
    for (int j = 0; j < 8; ++j) {
        float v = s[j] * r;
        s[j] = v > 0.f ? v : (__expf(v) - 1.f);
    }
    float4* o = reinterpret_cast<float4*>(out + (size_t)row * 512 + h * 128 + c8 * 8);
    o[0] = float4{s[0], s[1], s[2], s[3]};
    o[1] = float4{s[4], s[5], s[6], s[7]};
}

// ---------------- stage-2 reduce: out[row][d] = sum_h elu(rd_h[row] * part[h][row][d]) ----------------
__global__ __launch_bounds__(256) void reduce_h_elu_kernel(const u16* __restrict__ part,
                                                           float* __restrict__ out, int R, int H,
                                                           const float* __restrict__ rd) {
    int i = blockIdx.x * 256 + threadIdx.x;   // chunk over R*512/8
    int row = i >> 6, c8 = i & 63;
    long plane = (long)R * 512;
    const u16* p = part + (size_t)row * 512 + c8 * 8;
    float s[8] = {};
    for (int h = 0; h < H; ++h) {
        u16x8 x = *reinterpret_cast<const u16x8*>(p + (size_t)h * plane);
        float r = rd ? rd[(size_t)h * R + row] : 1.f;
#pragma unroll
        for (int j = 0; j < 8; ++j) {
            float v = bf2f(x[j]) * r;
            s[j] += v > 0.f ? v : (__expf(v) - 1.f);
        }
    }
    float4* o = reinterpret_cast<float4*>(out + (size_t)row * 512 + c8 * 8);
    o[0] = float4{s[0], s[1], s[2], s[3]};
    o[1] = float4{s[4], s[5], s[6], s[7]};
}

// ---------------- combines (float4) ----------------
__global__ __launch_bounds__(256) void combine_obj_kernel(const float4* __restrict__ feat,
        const float4* __restrict__ a, const float4* __restrict__ b,
        const float4* __restrict__ c, const float4* __restrict__ d,
        float4* __restrict__ out, ushort4* __restrict__ outbf) {
    int i = blockIdx.x * 256 + threadIdx.x;
    int r = i >> 8, c4 = i & 255;
    size_t half = (size_t)r * 128 + (c4 & 127);
    float4 t1 = (c4 < 128) ? a[half] : b[half];
    float4 t2 = (c4 < 128) ? c[half] : d[half];
    float4 f = feat[i];
    float4 o;
    o.x = (f.x + t1.x + t2.x) * (1.f / 3.f);
    o.y = (f.y + t1.y + t2.y) * (1.f / 3.f);
    o.z = (f.z + t1.z + t2.z) * (1.f / 3.f);
    o.w = (f.w + t1.w + t2.w) * (1.f / 3.f);
    out[i] = o;
    ushort4 ob; ob.x = f2bf(o.x); ob.y = f2bf(o.y); ob.z = f2bf(o.z); ob.w = f2bf(o.w);
    outbf[i] = ob;
}

__global__ __launch_bounds__(256) void combine_rel1_kernel(const float4* __restrict__ feat,
        const float4* __restrict__ a, const float4* __restrict__ b, ushort4* __restrict__ outbf) {
    int i = blockIdx.x * 256 + threadIdx.x;
    int r = i >> 8, c4 = i & 255;
    size_t half = (size_t)r * 128 + (c4 & 127);
    float4 t = (c4 < 128) ? a[half] : b[half];
    float4 f = feat[i];
    ushort4 ob;
    ob.x = f2bf((f.x + t.x) * 0.5f); ob.y = f2bf((f.y + t.y) * 0.5f);
    ob.z = f2bf((f.z + t.z) * 0.5f); ob.w = f2bf((f.w + t.w) * 0.5f);
    outbf[i] = ob;
}

__global__ __launch_bounds__(256) void combine_rel2_kernel(const float4* __restrict__ feat,
        const float4* __restrict__ a, const float4* __restrict__ b, float4* __restrict__ out) {
    int i = blockIdx.x * 256 + threadIdx.x;
    int r = i >> 8, c4 = i & 255;
    size_t half = (size_t)r * 128 + (c4 & 127);
    float4 t = (c4 < 128) ? a[half] : b[half];
    float4 f = feat[i];
    float4 o;
    o.x = (f.x + t.x) * 0.5f; o.y = (f.y + t.y) * 0.5f;
    o.z = (f.z + t.z) * 0.5f; o.w = (f.w + t.w) * 0.5f;
    out[i] = o;
}

extern "C" void kernel_launch(void* const* d_in, const int* in_sizes, int n_in,
                              void* d_out, int out_size, void* d_ws, size_t ws_size,
                              hipStream_t stream) {
    (void)in_sizes; (void)n_in; (void)out_size; (void)ws_size;
    const float* feat_obj = (const float*)d_in[0];
    const float* feat_rel = (const float*)d_in[1];
    const float* W_cat = (const float*)d_in[2];
    const float* b_cat = (const float*)d_in[3];
    const float* W_out = (const float*)d_in[4];
    const float* b_out = (const float*)d_in[5];
    float* out_obj = (float*)d_out;
    float* out_rel = (float*)d_out + (size_t)2048 * 1024;

    char* w = (char*)d_ws;
    auto alloc = [&](size_t bytes) { void* p = (void*)w; w += (bytes + 255) & ~(size_t)255; return p; };
    u16* bf_obj  = (u16*)alloc((size_t)2048 * 1024 * 2);
    u16* bf_rel  = (u16*)alloc((size_t)4096 * 1024 * 2);
    u16* bf_obj2 = (u16*)alloc((size_t)2048 * 1024 * 2);
    u16* bf_rel2 = (u16*)alloc((size_t)4096 * 1024 * 2);
    u16* Wt_cat  = (u16*)alloc((size_t)12 * 512 * 1024 * 2);     // 12 MiB
    u16* Wt2     = (u16*)alloc((size_t)4 * 3072 * 1024 * 2);     // 24 MiB
    u16* bufQV   = (u16*)alloc((size_t)2 * 2048 * 3072 * 2);     // 24 MiB
    u16* bufKV   = (u16*)alloc((size_t)2 * 2048 * 3072 * 2);     // 24 MiB
    u16* VTa     = (u16*)alloc((size_t)3072 * 2048 * 2);         // 12 MiB
    u16* VTb     = (u16*)alloc((size_t)512 * 4096 * 2);          // 4 MiB
    u16* VTs     = (u16*)alloc((size_t)3072 * 2048 * 2);         // 12 MiB (scaled V^T)
    u16* Sbuf    = (u16*)alloc((size_t)6 * 4096 * 2048 * 2);     // 96 MiB (expS planes)
    u16* PTbuf   = (u16*)alloc((size_t)4 * 2048 * 4096 * 2);     // 64 MiB (stage1 expS^T)
    u16* part    = (u16*)alloc((size_t)6 * 4096 * 512 * 2);      // 24 MiB bf16 partials
    float* rdH   = (float*)alloc((size_t)4 * 4096 * 4);
    float* rdQ   = (float*)alloc((size_t)6 * 2048 * 4);
    float* rdM   = (float*)alloc((size_t)6 * 4096 * 4);
    float* csP   = (float*)alloc((size_t)6 * 16 * 2048 * 4);
    float* sub_obj  = (float*)alloc((size_t)2048 * 512 * 4);
    float* obj_sub  = (float*)alloc((size_t)2048 * 512 * 4);
    float* sub_rel  = (float*)alloc((size_t)2048 * 512 * 4);
    float* obj_rel  = (float*)alloc((size_t)2048 * 512 * 4);
    float* rel_obj  = (float*)alloc((size_t)4096 * 512 * 4);
    float* rel_sub  = (float*)alloc((size_t)4096 * 512 * 4);
    float* rel_obj2 = (float*)alloc((size_t)4096 * 512 * 4);
    float* rel_sub2 = (float*)alloc((size_t)4096 * 512 * 4);

    cvt_bf16_kernel<<<2048, 256, 0, stream>>>((const float4*)feat_obj, (ushort4*)bf_obj, 2048 * 1024 / 4);
    cvt_bf16_kernel<<<4096, 256, 0, stream>>>((const float4*)feat_rel, (ushort4*)bf_rel, 4096 * 1024 / 4);
    transcvt_kernel<<<dim3(16, 32, 12), dim3(32, 8), 0, stream>>>(W_cat, Wt_cat, 1024, 512);

    const float sc1 = 0.08838834764831845f;  // 1/sqrt(128)
    const float sc2 = 0.04419417382415922f;  // 1/sqrt(512)
    const long planeW = (long)512 * 1024;
    const long planeW2 = (long)3072 * 1024;
    const long NIL = 0;

    // ---------------- stage 1: three concat=True MHAs, h=4, d_k=128 ----------------
    struct MhaCfg { const u16* xq; const u16* xk; int Nq, Nk; float* d1; float* d2; int mask; };
    MhaCfg cfg[3] = {
        { bf_obj, bf_obj, 2048, 2048, sub_obj, obj_sub, 1 },
        { bf_obj, bf_rel, 2048, 4096, sub_rel, rel_sub, 0 },
        { bf_rel, bf_obj, 4096, 2048, rel_obj, obj_rel, 0 },
    };
    for (int m = 0; m < 3; ++m) {
        const u16* Wt = Wt_cat + (size_t)m * 4 * planeW;
        const float* bb = b_cat + m * 4 * 512;
        int Nq = cfg[m].Nq, Nk = cfg[m].Nk;
        long splane = (long)Nq * Nk;
        // projections: z=0 -> {q,k}, z=1 -> {qv,kv}
        gemm_nt<E_PROJ, 64><<<dim3(Nq / 64, 8, 2), 256, 0, stream>>>(
            cfg[m].xq, Wt, bufQV, bb, Nq, 512, 1024, 1024, 1024, 512, 0.f,
            0, 2 * planeW, (long)Nq * 512, 1024, 1, NIL, NIL);
        gemm_nt<E_PROJ, 64><<<dim3(Nk / 64, 8, 2), 256, 0, stream>>>(
            cfg[m].xk, Wt + planeW, bufKV, bb + 512, Nk, 512, 1024, 1024, 1024, 512, 0.f,
            0, 2 * planeW, (long)Nk * 512, 1024, 1, NIL, NIL);
        // V transposes: kv^T [512][Nk], qv^T [512][Nq]
        transpose_bf16_kernel<<<dim3(Nk / 64, 8, 1), 256, 0, stream>>>(
            bufKV + (size_t)Nk * 512, VTa, Nk, 512, 0);
        transpose_bf16_kernel<<<dim3(Nq / 64, 8, 1), 256, 0, stream>>>(
            bufQV + (size_t)Nq * 512, VTb, Nq, 512, 0);
        // expS = exp(scale * Q K^T), 4 heads
        if (cfg[m].mask)
            gemm_nt<E_EXPM, 128><<<dim3(Nq / 128, Nk / 128, 4), 256, 0, stream>>>(
                bufQV, bufKV, Sbuf, nullptr, Nq, Nk, 128, 512, 512, Nk, sc1,
                128, 128, splane, NIL, 1, NIL, NIL);
        else
            gemm_nt<E_EXP, 128><<<dim3(Nq / 128, Nk / 128, 4), 256, 0, stream>>>(
                bufQV, bufKV, Sbuf, nullptr, Nq, Nk, 128, 512, 512, Nk, sc1,
                128, 128, splane, NIL, 1, NIL, NIL);
        // rdH[h][q] = 1/rowsum
        rowsum_inv_kernel<<<dim3(Nq, 4), 256, 0, stream>>>(Sbuf, rdH, Nk, splane, Nq);
        // expS^T for a2
        transpose_bf16_kernel<<<dim3(Nq / 64, Nk / 64, 4), 256, 0, stream>>>(Sbuf, PTbuf, Nq, Nk, splane);
        // VTs = qv^T with columns q scaled by rdH[h][q]
        scale_rows_kernel<<<512 * Nq / 2048, 256, 0, stream>>>(VTb, VTs, rdH, Nq, 7);
        // a1 partials: z = h*KZ1+kc, each (Nq x 128) = expS[h][:, kc*Kc1:...] @ kv^T[h]
        int KZ1 = (Nq == 2048) ? 4 : 2;  int Kc1 = Nk / KZ1;
        gemm_nt<E_PART, 128><<<dim3(Nq / 128, 1, 4 * KZ1), 256, 0, stream>>>(
            Sbuf, VTa, part, nullptr, Nq, 128, Kc1, Nk, Nk, 128, 0.f,
            splane, 128L * Nk, (long)Nq * 128, NIL, KZ1, Kc1, Kc1);
        reduce_kc_elu_kernel<<<Nq / 4, 256, 0, stream>>>(part, cfg[m].d1, Nq, KZ1, rdH);
        // a2 partials: z = h*KZ2+kc, each (Nk x 128) = expS^T[h][:, kc*Kc2:...] @ qv'^T[h]
        int KZ2 = (Nk == 2048) ? 4 : 2;  int Kc2 = Nq / KZ2;
        gemm_nt<E_PART, 128><<<dim3(Nk / 128, 1, 4 * KZ2), 256, 0, stream>>>(
            PTbuf, VTs, part, nullptr, Nk, 128, Kc2, Nq, Nq, 128, 0.f,
            splane, 128L * Nq, (long)Nk * 128, NIL, KZ2, Kc2, Kc2);
        reduce_kc_elu_kernel<<<Nk / 4, 256, 0, stream>>>(part, cfg[m].d2, Nk, KZ2, nullptr);
    }

    combine_obj_kernel<<<2048, 256, 0, stream>>>((const float4*)feat_obj, (const float4*)sub_obj,
        (const float4*)obj_sub, (const float4*)sub_rel, (const float4*)obj_rel,
        (float4*)out_obj, (ushort4*)bf_obj2);
    combine_rel1_kernel<<<4096, 256, 0, stream>>>((const float4*)feat_rel, (const float4*)rel_obj,
        (const float4*)rel_sub, (ushort4*)bf_rel2);

    const long spl2 = (long)4096 * 2048;   // stage-2 score plane
    const long vpl2 = (long)4096 * 512;    // stage-2 part plane

    // ---------------- stage 2 mha0: xq=obj2 (2048), xk=rel2 (4096); a2 only ----------------
    {
        transcvt_kernel<<<dim3(96, 32, 3), dim3(32, 8), 0, stream>>>(W_out, Wt2, 1024, 3072);
        // z=0 -> q (W0,b0), z=1 -> qv (W2,b2)
        gemm_nt<E_PROJ, 128><<<dim3(16, 24, 2), 256, 0, stream>>>(
            bf_obj2, Wt2, bufQV, b_out, 2048, 3072, 1024, 1024, 1024, 3072, 0.f,
            0, 2 * planeW2, (long)2048 * 3072, 2L * 3072, 1, NIL, NIL);
        gemm_nt<E_PROJ, 128><<<dim3(32, 24, 1), 256, 0, stream>>>(
            bf_rel2, Wt2 + planeW2, bufKV, b_out + 3072, 4096, 3072, 1024,
            1024, 1024, 3072, 0.f, 0, 0, 0, NIL, 1, NIL, NIL);
        transpose_bf16_kernel<<<dim3(32, 48, 1), 256, 0, stream>>>(
            bufQV + (size_t)2048 * 3072, VTa, 2048, 3072, 0);   // qv^T [3072][2048]
        // swapped scores: expS'[h][m_key][q] = exp(sc2 * K Q^T), 6 heads
        gemm_nt<E_EXP, 128><<<dim3(32, 16, 6), 256, 0, stream>>>(
            bufKV, bufQV, Sbuf, nullptr, 4096, 2048, 512, 3072, 3072, 2048, sc2,
            512, 512, spl2, NIL, 1, NIL, NIL);
        // rdQ[h][q] = 1/colsum(expS'[h])
        colsum_part_kernel<<<dim3(8, 16, 6), 256, 0, stream>>>(Sbuf, csP, 4096, 2048, 256, 16);
        colsum_fin_kernel<<<dim3(8, 6), 256, 0, stream>>>(csP, rdQ, 2048, 16);
        // VTs = qv^T with columns q scaled by rdQ[h][q] (dk=512 rows/head)
        scale_rows_kernel<<<3072 * 2048 / 2048, 256, 0, stream>>>(VTa, VTs, rdQ, 2048, 9);
        // part[h] = expS'[h] @ (scaled qv^T)[h]
        gemm_nt<E_PART, 128><<<dim3(32, 4, 6), 256, 0, stream>>>(
            Sbuf, VTs, part, nullptr, 4096, 512, 2048, 2048, 2048, 512, 0.f,
            spl2, 512L * 2048, vpl2, NIL, 1, NIL, NIL);
        reduce_h_elu_kernel<<<1024, 256, 0, stream>>>(part, rel_sub2, 4096, 6, nullptr);
    }
    // ---------------- stage 2 mha1: xq=rel2 (4096), xk=obj2 (2048); a1 only ----------------
    {
        transcvt_kernel<<<dim3(96, 32, 4), dim3(32, 8), 0, stream>>>(W_out + 4 * planeW2, Wt2, 1024, 3072);
        gemm_nt<E_PROJ, 128><<<dim3(32, 24, 1), 256, 0, stream>>>(
            bf_rel2, Wt2, bufQV, b_out + 4 * 3072, 4096, 3072, 1024,
            1024, 1024, 3072, 0.f, 0, 0, 0, NIL, 1, NIL, NIL);
        // z=0 -> k (W1,b1), z=1 -> kv (W3,b3)
        gemm_nt<E_PROJ, 128><<<dim3(16, 24, 2), 256, 0, stream>>>(
            bf_obj2, Wt2 + planeW2, bufKV, b_out + 5 * 3072, 2048, 3072, 1024,
            1024, 1024, 3072, 0.f, 0, 2 * planeW2, (long)2048 * 3072, 2L * 3072, 1, NIL, NIL);
        transpose_bf16_kernel<<<dim3(32, 48, 1), 256, 0, stream>>>(
            bufKV + (size_t)2048 * 3072, VTa, 2048, 3072, 0);   // kv^T [3072][2048]
        // scores: expS[h][q_rel][k_obj], 6 heads
        gemm_nt<E_EXP, 128><<<dim3(32, 16, 6), 256, 0, stream>>>(
            bufQV, bufKV, Sbuf, nullptr, 4096, 2048, 512, 3072, 3072, 2048, sc2,
            512, 512, spl2, NIL, 1, NIL, NIL);
        // rdM[h][row] = 1/rowsum
        rowsum_inv_kernel<<<dim3(4096, 6), 256, 0, stream>>>(Sbuf, rdM, 2048, spl2, 4096);
        // part[h] = expS[h] @ kv^T[h]; rd applied in reduce
        gemm_nt<E_PART, 128><<<dim3(32, 4, 6), 256, 0, stream>>>(
            Sbuf, VTa, part, nullptr, 4096, 512, 2048, 2048, 2048, 512, 0.f,
            spl2, 512L * 2048, vpl2, NIL, 1, NIL, NIL);
        reduce_h_elu_kernel<<<1024, 256, 0, stream>>>(part, rel_obj2, 4096, 6, rdM);
    }

    combine_rel2_kernel<<<4096, 256, 0, stream>>>((const float4*)feat_rel, (const float4*)rel_obj2,
        (const float4*)rel_sub2, (float4*)out_rel);
}

// Round 7
// 1014.031 us; speedup vs baseline: 1.0463x; 1.0463x over previous
//
#include <hip/hip_runtime.h>

typedef unsigned short u16;
typedef unsigned int u32;
typedef __attribute__((ext_vector_type(4))) float f32x4;
typedef __attribute__((ext_vector_type(8))) __bf16 bf16x8;
typedef __attribute__((ext_vector_type(8))) unsigned short u16x8;

#if defined(__has_builtin)
#if __has_builtin(__builtin_amdgcn_global_load_lds)
#define HAS_GLL 1
#endif
#endif

__device__ __forceinline__ u16 f2bf(float f) {
    u32 u = __builtin_bit_cast(u32, f);
    u += 0x7fffu + ((u >> 16) & 1u);
    return (u16)(u >> 16);
}
__device__ __forceinline__ float bf2f(u16 x) {
    return __builtin_bit_cast(float, (u32)x << 16);
}

// counted-vmcnt barrier: wait until <= N vector-memory ops outstanding, then barrier.
template <int N> __device__ __forceinline__ void wbar() {
#ifdef HAS_GLL
    if constexpr (N == 0)
        asm volatile("s_waitcnt vmcnt(0)\n\ts_barrier" ::: "memory");
    else if constexpr (N == 2)
        asm volatile("s_waitcnt vmcnt(2)\n\ts_barrier" ::: "memory");
    else
        asm volatile("s_waitcnt vmcnt(4)\n\ts_barrier" ::: "memory");
#else
    __syncthreads();
#endif
}

// ---------------- elementwise conversion ----------------
__global__ __launch_bounds__(256) void cvt_bf16_kernel(const float4* __restrict__ in,
                                                       ushort4* __restrict__ out, int n4) {
    int i = blockIdx.x * 256 + threadIdx.x;
    if (i < n4) {
        float4 v = in[i];
        ushort4 o;
        o.x = f2bf(v.x); o.y = f2bf(v.y); o.z = f2bf(v.z); o.w = f2bf(v.w);
        out[i] = o;
    }
}

// transpose + convert: W [B][K][N] f32 -> Wt [B][N][K] bf16
__global__ __launch_bounds__(256) void transcvt_kernel(const float* __restrict__ W,
                                                       u16* __restrict__ Wt, int K, int N) {
    __shared__ u16 t[32][33];
    int b = blockIdx.z;
    const float* Wb = W + (size_t)b * K * N;
    u16* Wtb = Wt + (size_t)b * K * N;
    int n0 = blockIdx.x * 32, k0 = blockIdx.y * 32;
    int tx = threadIdx.x, ty = threadIdx.y;
#pragma unroll
    for (int j = 0; j < 4; ++j)
        t[ty + j * 8][tx] = f2bf(Wb[(size_t)(k0 + ty + j * 8) * N + n0 + tx]);
    __syncthreads();
#pragma unroll
    for (int j = 0; j < 4; ++j)
        Wtb[(size_t)(n0 + ty + j * 8) * K + k0 + tx] = t[tx][ty + j * 8];
}

// bf16 transpose per z-plane: in [z][R][C] -> out [z][C][R]
__global__ __launch_bounds__(256) void transpose_bf16_kernel(const u16* __restrict__ in,
                                                             u16* __restrict__ out, int R, int C,
                                                             long plane) {
    __shared__ u16 t[64][65];
    const u16* inz = in + (size_t)blockIdx.z * plane;
    u16* outz = out + (size_t)blockIdx.z * plane;
    int r0 = blockIdx.x * 64, c0 = blockIdx.y * 64;
    int tx = threadIdx.x & 15, ty = threadIdx.x >> 4;
#pragma unroll
    for (int j = 0; j < 4; ++j) {
        int r = ty + j * 16;
        ushort4 v = *reinterpret_cast<const ushort4*>(inz + (size_t)(r0 + r) * C + c0 + tx * 4);
        t[r][tx * 4 + 0] = v.x; t[r][tx * 4 + 1] = v.y;
        t[r][tx * 4 + 2] = v.z; t[r][tx * 4 + 3] = v.w;
    }
    __syncthreads();
#pragma unroll
    for (int j = 0; j < 4; ++j) {
        int c = ty + j * 16;
        ushort4 v;
        v.x = t[tx * 4 + 0][c]; v.y = t[tx * 4 + 1][c];
        v.z = t[tx * 4 + 2][c]; v.w = t[tx * 4 + 3][c];
        *reinterpret_cast<ushort4*>(outz + (size_t)(c0 + c) * R + r0 + tx * 4) = v;
    }
}

// ---------------- rd[z][row] = 1 / sum_col expS[z][row][col] ----------------
__global__ __launch_bounds__(256) void rowsum_inv_kernel(const u16* __restrict__ S,
                                                         float* __restrict__ rd, int N,
                                                         long plane, int R) {
    int row = blockIdx.x, z = blockIdx.y;
    const u16* s = S + (size_t)z * plane + (size_t)row * N;
    int tid = threadIdx.x, lane = tid & 63, wid = tid >> 6;
    int cnt = N >> 11;
    __shared__ float red[4];
    float sum = 0.f;
    for (int c = 0; c < cnt; ++c) {
        u16x8 x = *reinterpret_cast<const u16x8*>(s + c * 2048 + tid * 8);
#pragma unroll
        for (int j = 0; j < 8; ++j) sum += bf2f(x[j]);
    }
#pragma unroll
    for (int off = 32; off; off >>= 1) sum += __shfl_down(sum, off);
    if (lane == 0) red[wid] = sum;
    __syncthreads();
    if (tid == 0) rd[(size_t)z * R + row] = 1.f / (red[0] + red[1] + red[2] + red[3]);
}

// ---------------- column-sum partials ----------------
__global__ __launch_bounds__(256) void colsum_part_kernel(const u16* __restrict__ S,
                                                          float* __restrict__ partial,
                                                          int R, int C, int rchunk, int nrb) {
    int col = blockIdx.x * 256 + threadIdx.x;
    int rb = blockIdx.y, z = blockIdx.z;
    const u16* s = S + (size_t)z * R * C + (size_t)rb * rchunk * C + col;
    float sum = 0.f;
    for (int r = 0; r < rchunk; ++r) sum += bf2f(s[(size_t)r * C]);
    partial[((size_t)z * nrb + rb) * C + col] = sum;
}

__global__ __launch_bounds__(256) void colsum_fin_kernel(const float* __restrict__ partial,
                                                         float* __restrict__ rd, int C, int nrb) {
    int col = blockIdx.x * 256 + threadIdx.x;
    int z = blockIdx.y;
    float sum = 0.f;
    for (int rb = 0; rb < nrb; ++rb) sum += partial[((size_t)z * nrb + rb) * C + col];
    rd[(size_t)z * C + col] = 1.f / sum;
}

// ---------------- scale rows of a [R][C] bf16 matrix by rd[(r>>lg)·C + c] ----------------
__global__ __launch_bounds__(256) void scale_rows_kernel(const u16* __restrict__ in,
                                                         u16* __restrict__ out,
                                                         const float* __restrict__ rd,
                                                         int C, int lgdk) {
    int i = (blockIdx.x * 256 + threadIdx.x) * 8;
    int r = i / C, c = i % C;
    const float* rdp = rd + ((size_t)(r >> lgdk)) * C + c;
    u16x8 x = *reinterpret_cast<const u16x8*>(in + i);
    u16x8 o;
#pragma unroll
    for (int j = 0; j < 8; ++j) o[j] = f2bf(bf2f(x[j]) * rdp[j]);
    *reinterpret_cast<u16x8*>(out + i) = o;
}

// ---------------- GEMM: C = A (M,K) * B^T (N,K), row-major ----------------
// 3-deep LDS ring, counted-vmcnt pipeline: stage(t+2) issued before compute(t);
// barrier waits vmcnt(LOADS) so the newest stage's loads stay in flight across it.
// z = hz*ZK + kz: A += hz*sAz + kz*sAz2, B += hz*sBz + kz*sBz2, C elem += z*sCz, bias += z*sBias.
enum { E_PROJ = 0, E_EXP, E_EXPM, E_PART };

template <int EPI, int BM>
__global__ __launch_bounds__(256) void gemm_nt(const u16* __restrict__ A, const u16* __restrict__ B,
                                               void* __restrict__ Cv, const float* __restrict__ bias,
                                               int M, int N, int K, int lda, int ldb, int ldc,
                                               float scale, long sAz, long sBz, long sCz,
                                               long sBias, int ZK, long sAz2, long sBz2) {
    constexpr int MF = BM / 32;               // 16x16 frags per wave dim
    constexpr int ITERS = BM * 32 / (256 * 8);
    constexpr int LOADS = ITERS * 2;          // gload_lds per thread per stage()
    constexpr int SM_STAGE = 3 * BM * 64;     // 3 ring buffers of (A+B)
    constexpr int SM_REPACK = BM * BM;
    __shared__ __align__(16) u16 smem[SM_STAGE > SM_REPACK ? SM_STAGE : SM_REPACK];
    const int tid = threadIdx.x;
    const int lane = tid & 63;
    const int wid = tid >> 6;
    const int wr = (wid >> 1) * (BM / 2);
    const int wc = (wid & 1) * (BM / 2);
    const int row0 = blockIdx.x * BM;
    const int col0 = blockIdx.y * BM;
    const long zo = blockIdx.z;
    const long hz = zo / ZK;
    const long kz = zo - hz * ZK;
    const u16* Az = A + hz * sAz + kz * sAz2;
    const u16* Bz = B + hz * sBz + kz * sBz2;
    const long zoff = zo * sCz;
    const float* biasz = bias ? bias + zo * sBias : nullptr;
    f32x4 acc[MF][MF] = {};

    auto As = [&](int buf) { return smem + buf * (BM * 64); };
    auto Bs = [&](int buf) { return smem + buf * (BM * 64) + BM * 32; };

    auto stage = [&](int buf, int k0) {
#pragma unroll
        for (int i = 0; i < ITERS; ++i) {
            int c = tid + i * 256;
            int r = c >> 2;
            int lch = (c & 3) ^ ((r >> 1) & 3);   // logical k-chunk at this physical slot
            const u16* sa = Az + (size_t)(row0 + r) * lda + k0 + lch * 8;
            const u16* sb = Bz + (size_t)(col0 + r) * ldb + k0 + lch * 8;
#ifdef HAS_GLL
            __builtin_amdgcn_global_load_lds(
                (const __attribute__((address_space(1))) void*)sa,
                (__attribute__((address_space(3))) void*)(&As(buf)[c * 8]), 16, 0, 0);
            __builtin_amdgcn_global_load_lds(
                (const __attribute__((address_space(1))) void*)sb,
                (__attribute__((address_space(3))) void*)(&Bs(buf)[c * 8]), 16, 0, 0);
#else
            *reinterpret_cast<uint4*>(&As(buf)[c * 8]) = *reinterpret_cast<const uint4*>(sa);
            *reinterpret_cast<uint4*>(&Bs(buf)[c * 8]) = *reinterpret_cast<const uint4*>(sb);
#endif
        }
    };

    // prologue: fill ring slots 0 and 1 (all K used here are >= 128 -> nsteps >= 4)
    stage(0, 0);
    stage(1, 32);
    wbar<LOADS>();                 // slot 0 ready; slot 1 may still be in flight

    const int nsteps = K >> 5;
    for (int t = 0; t < nsteps; ++t) {
        const int bufc = t % 3;
        const bool more2 = (t + 2 < nsteps);
        if (more2) stage((t + 2) % 3, (t + 2) << 5);   // issue loads first
        bf16x8 af[MF], bv[MF];
#pragma unroll
        for (int m = 0; m < MF; ++m) {
            int rr = wr + m * 16 + (lane & 15);
            int p = (lane >> 4) ^ ((rr >> 1) & 3);
            af[m] = *reinterpret_cast<const bf16x8*>(&As(bufc)[rr * 32 + p * 8]);
        }
#pragma unroll
        for (int n = 0; n < MF; ++n) {
            int rr = wc + n * 16 + (lane & 15);
            int p = (lane >> 4) ^ ((rr >> 1) & 3);
            bv[n] = *reinterpret_cast<const bf16x8*>(&Bs(bufc)[rr * 32 + p * 8]);
        }
#pragma unroll
        for (int m = 0; m < MF; ++m)
#pragma unroll
            for (int n = 0; n < MF; ++n)
                acc[m][n] = __builtin_amdgcn_mfma_f32_16x16x32_bf16(af[m], bv[n], acc[m][n], 0, 0, 0);
        if (more2)                 wbar<LOADS>();   // (t+1) slot ready; (t+2) still flying
        else if (t + 1 < nsteps)   wbar<0>();       // drain: (t+1) slot ready
        else                       __syncthreads(); // protect LDS reuse by repack epilogue
    }

    // ---- epilogue: math + LDS repack (swizzled) + coalesced b128 stores ----
    char* lc = reinterpret_cast<char*>(smem);
#pragma unroll
    for (int m = 0; m < MF; ++m) {
#pragma unroll
        for (int n = 0; n < MF; ++n) {
#pragma unroll
            for (int j = 0; j < 4; ++j) {
                int lrow = wr + m * 16 + ((lane >> 4) << 2) + j;
                int lcol = wc + n * 16 + (lane & 15);
                float v = acc[m][n][j];
                if (EPI == E_PROJ) {
                    v += biasz[lcol + col0];
                } else if (EPI == E_EXP || EPI == E_EXPM) {
                    v = __expf(v * scale);
                    if (EPI == E_EXPM && row0 + lrow == col0 + lcol) v = 0.f;
                }
                u32 byte = (u32)((lrow * BM + lcol) * 2) ^ (((lrow >> 2) & 3) << 5);
                *reinterpret_cast<u16*>(lc + byte) = f2bf(v);
            }
        }
    }
    __syncthreads();
    constexpr int CH = BM / 8;            // u16x8 chunks per row
    constexpr int NIT = BM * CH / 256;
    u16* Cp = reinterpret_cast<u16*>(Cv) + zoff;
#pragma unroll
    for (int it = 0; it < NIT; ++it) {
        int idx = it * 256 + tid;
        int rrow = idx / CH, c8 = idx % CH;
        u32 byte = (u32)((rrow * BM + c8 * 8) * 2) ^ (((rrow >> 2) & 3) << 5);
        u16x8 val = *reinterpret_cast<const u16x8*>(lc + byte);
        *reinterpret_cast<u16x8*>(Cp + (size_t)(row0 + rrow) * ldc + col0 + c8 * 8) = val;
    }
}

// ---------------- stage-1 reduce: out[row][h*128+d] = elu(rd_h[row] * sum_kc part[h,kc]) ----------------
__global__ __launch_bounds__(256) void reduce_kc_elu_kernel(const u16* __restrict__ part,
                                                            float* __restrict__ out, int M, int KZ,
                                                            const float* __restrict__ rd) {
    int i = blockIdx.x * 256 + threadIdx.x;   // chunk over M*512/8
    int row = i >> 6;
    int hc = i & 63;
    int h = hc >> 4, c8 = hc & 15;
    long plane = (long)M * 128;
    const u16* p = part + (size_t)(h * KZ) * plane + (size_t)row * 128 + c8 * 8;
    float s[8] = {};
    for (int kc = 0; kc < KZ; ++kc) {
        u16x8 x = *reinterpret_cast<const u16x8*>(p + (size_t)kc * plane);
#pragma unroll
        for (int j = 0; j < 8; ++j) s[j] += bf2f(x[j]);
    }
    float r = rd ? rd[(size_t)h * M + row] : 1.f;
#pragma unroll
    for (int j = 0; j < 8; ++j) {
        float v = s[j] * r;
        s[j] = v > 0.f ? v : (__expf(v) - 1.f);
    }
    float4* o = reinterpret_cast<float4*>(out + (size_t)row * 512 + h * 128 + c8 * 8);
    o[0] = float4{s[0], s[1], s[2], s[3]};
    o[1] = float4{s[4], s[5], s[6], s[7]};
}

// ---------------- stage-2 reduce: out[row][d] = sum_h elu(rd_h[row] * part[h][row][d]) ----------------
__global__ __launch_bounds__(256) void reduce_h_elu_kernel(const u16* __restrict__ part,
                                                           float* __restrict__ out, int R, int H,
                                                           const float* __restrict__ rd) {
    int i = blockIdx.x * 256 + threadIdx.x;   // chunk over R*512/8
    int row = i >> 6, c8 = i & 63;
    long plane = (long)R * 512;
    const u16* p = part + (size_t)row * 512 + c8 * 8;
    float s[8] = {};
    for (int h = 0; h < H; ++h) {
        u16x8 x = *reinterpret_cast<const u16x8*>(p + (size_t)h * plane);
        float r = rd ? rd[(size_t)h * R + row] : 1.f;
#pragma unroll
        for (int j = 0; j < 8; ++j) {
            float v = bf2f(x[j]) * r;
            s[j] += v > 0.f ? v : (__expf(v) - 1.f);
        }
    }
    float4* o = reinterpret_cast<float4*>(out + (size_t)row * 512 + c8 * 8);
    o[0] = float4{s[0], s[1], s[2], s[3]};
    o[1] = float4{s[4], s[5], s[6], s[7]};
}

// ---------------- combines (float4) ----------------
__global__ __launch_bounds__(256) void combine_obj_kernel(const float4* __restrict__ feat,
        const float4* __restrict__ a, const float4* __restrict__ b,
        const float4* __restrict__ c, const float4* __restrict__ d,
        float4* __restrict__ out, ushort4* __restrict__ outbf) {
    int i = blockIdx.x * 256 + threadIdx.x;
    int r = i >> 8, c4 = i & 255;
    size_t half = (size_t)r * 128 + (c4 & 127);
    float4 t1 = (c4 < 128) ? a[half] : b[half];
    float4 t2 = (c4 < 128) ? c[half] : d[half];
    float4 f = feat[i];
    float4 o;
    o.x = (f.x + t1.x + t2.x) * (1.f / 3.f);
    o.y = (f.y + t1.y + t2.y) * (1.f / 3.f);
    o.z = (f.z + t1.z + t2.z) * (1.f / 3.f);
    o.w = (f.w + t1.w + t2.w) * (1.f / 3.f);
    out[i] = o;
    ushort4 ob; ob.x = f2bf(o.x); ob.y = f2bf(o.y); ob.z = f2bf(o.z); ob.w = f2bf(o.w);
    outbf[i] = ob;
}

__global__ __launch_bounds__(256) void combine_rel1_kernel(const float4* __restrict__ feat,
        const float4* __restrict__ a, const float4* __restrict__ b, ushort4* __restrict__ outbf) {
    int i = blockIdx.x * 256 + threadIdx.x;
    int r = i >> 8, c4 = i & 255;
    size_t half = (size_t)r * 128 + (c4 & 127);
    float4 t = (c4 < 128) ? a[half] : b[half];
    float4 f = feat[i];
    ushort4 ob;
    ob.x = f2bf((f.x + t.x) * 0.5f); ob.y = f2bf((f.y + t.y) * 0.5f);
    ob.z = f2bf((f.z + t.z) * 0.5f); ob.w = f2bf((f.w + t.w) * 0.5f);
    outbf[i] = ob;
}

__global__ __launch_bounds__(256) void combine_rel2_kernel(const float4* __restrict__ feat,
        const float4* __restrict__ a, const float4* __restrict__ b, float4* __restrict__ out) {
    int i = blockIdx.x * 256 + threadIdx.x;
    int r = i >> 8, c4 = i & 255;
    size_t half = (size_t)r * 128 + (c4 & 127);
    float4 t = (c4 < 128) ? a[half] : b[half];
    float4 f = feat[i];
    float4 o;
    o.x = (f.x + t.x) * 0.5f; o.y = (f.y + t.y) * 0.5f;
    o.z = (f.z + t.z) * 0.5f; o.w = (f.w + t.w) * 0.5f;
    out[i] = o;
}

extern "C" void kernel_launch(void* const* d_in, const int* in_sizes, int n_in,
                              void* d_out, int out_size, void* d_ws, size_t ws_size,
                              hipStream_t stream) {
    (void)in_sizes; (void)n_in; (void)out_size; (void)ws_size;
    const float* feat_obj = (const float*)d_in[0];
    const float* feat_rel = (const float*)d_in[1];
    const float* W_cat = (const float*)d_in[2];
    const float* b_cat = (const float*)d_in[3];
    const float* W_out = (const float*)d_in[4];
    const float* b_out = (const float*)d_in[5];
    float* out_obj = (float*)d_out;
    float* out_rel = (float*)d_out + (size_t)2048 * 1024;

    char* w = (char*)d_ws;
    auto alloc = [&](size_t bytes) { void* p = (void*)w; w += (bytes + 255) & ~(size_t)255; return p; };
    u16* bf_obj  = (u16*)alloc((size_t)2048 * 1024 * 2);
    u16* bf_rel  = (u16*)alloc((size_t)4096 * 1024 * 2);
    u16* bf_obj2 = (u16*)alloc((size_t)2048 * 1024 * 2);
    u16* bf_rel2 = (u16*)alloc((size_t)4096 * 1024 * 2);
    u16* Wt_cat  = (u16*)alloc((size_t)12 * 512 * 1024 * 2);     // 12 MiB
    u16* Wt2     = (u16*)alloc((size_t)4 * 3072 * 1024 * 2);     // 24 MiB
    u16* bufQV   = (u16*)alloc((size_t)2 * 2048 * 3072 * 2);     // 24 MiB
    u16* bufKV   = (u16*)alloc((size_t)2 * 2048 * 3072 * 2);     // 24 MiB
    u16* VTa     = (u16*)alloc((size_t)3072 * 2048 * 2);         // 12 MiB
    u16* VTb     = (u16*)alloc((size_t)512 * 4096 * 2);          // 4 MiB
    u16* VTs     = (u16*)alloc((size_t)3072 * 2048 * 2);         // 12 MiB (scaled V^T)
    u16* Sbuf    = (u16*)alloc((size_t)6 * 4096 * 2048 * 2);     // 96 MiB (expS planes)
    u16* PTbuf   = (u16*)alloc((size_t)4 * 2048 * 4096 * 2);     // 64 MiB (stage1 expS^T)
    u16* part    = (u16*)alloc((size_t)6 * 4096 * 512 * 2);      // 24 MiB bf16 partials
    float* rdH   = (float*)alloc((size_t)4 * 4096 * 4);
    float* rdQ   = (float*)alloc((size_t)6 * 2048 * 4);
    float* rdM   = (float*)alloc((size_t)6 * 4096 * 4);
    float* csP   = (float*)alloc((size_t)6 * 16 * 2048 * 4);
    float* sub_obj  = (float*)alloc((size_t)2048 * 512 * 4);
    float* obj_sub  = (float*)alloc((size_t)2048 * 512 * 4);
    float* sub_rel  = (float*)alloc((size_t)2048 * 512 * 4);
    float* obj_rel  = (float*)alloc((size_t)2048 * 512 * 4);
    float* rel_obj  = (float*)alloc((size_t)4096 * 512 * 4);
    float* rel_sub  = (float*)alloc((size_t)4096 * 512 * 4);
    float* rel_obj2 = (float*)alloc((size_t)4096 * 512 * 4);
    float* rel_sub2 = (float*)alloc((size_t)4096 * 512 * 4);

    cvt_bf16_kernel<<<2048, 256, 0, stream>>>((const float4*)feat_obj, (ushort4*)bf_obj, 2048 * 1024 / 4);
    cvt_bf16_kernel<<<4096, 256, 0, stream>>>((const float4*)feat_rel, (ushort4*)bf_rel, 4096 * 1024 / 4);
    transcvt_kernel<<<dim3(16, 32, 12), dim3(32, 8), 0, stream>>>(W_cat, Wt_cat, 1024, 512);

    const float sc1 = 0.08838834764831845f;  // 1/sqrt(128)
    const float sc2 = 0.04419417382415922f;  // 1/sqrt(512)
    const long planeW = (long)512 * 1024;
    const long planeW2 = (long)3072 * 1024;
    const long NIL = 0;

    // ---------------- stage 1: three concat=True MHAs, h=4, d_k=128 ----------------
    struct MhaCfg { const u16* xq; const u16* xk; int Nq, Nk; float* d1; float* d2; int mask; };
    MhaCfg cfg[3] = {
        { bf_obj, bf_obj, 2048, 2048, sub_obj, obj_sub, 1 },
        { bf_obj, bf_rel, 2048, 4096, sub_rel, rel_sub, 0 },
        { bf_rel, bf_obj, 4096, 2048, rel_obj, obj_rel, 0 },
    };
    for (int m = 0; m < 3; ++m) {
        const u16* Wt = Wt_cat + (size_t)m * 4 * planeW;
        const float* bb = b_cat + m * 4 * 512;
        int Nq = cfg[m].Nq, Nk = cfg[m].Nk;
        long splane = (long)Nq * Nk;
        // projections: z=0 -> {q,k}, z=1 -> {qv,kv}
        gemm_nt<E_PROJ, 64><<<dim3(Nq / 64, 8, 2), 256, 0, stream>>>(
            cfg[m].xq, Wt, bufQV, bb, Nq, 512, 1024, 1024, 1024, 512, 0.f,
            0, 2 * planeW, (long)Nq * 512, 1024, 1, NIL, NIL);
        gemm_nt<E_PROJ, 64><<<dim3(Nk / 64, 8, 2), 256, 0, stream>>>(
            cfg[m].xk, Wt + planeW, bufKV, bb + 512, Nk, 512, 1024, 1024, 1024, 512, 0.f,
            0, 2 * planeW, (long)Nk * 512, 1024, 1, NIL, NIL);
        // V transposes: kv^T [512][Nk], qv^T [512][Nq]
        transpose_bf16_kernel<<<dim3(Nk / 64, 8, 1), 256, 0, stream>>>(
            bufKV + (size_t)Nk * 512, VTa, Nk, 512, 0);
        transpose_bf16_kernel<<<dim3(Nq / 64, 8, 1), 256, 0, stream>>>(
            bufQV + (size_t)Nq * 512, VTb, Nq, 512, 0);
        // expS = exp(scale * Q K^T), 4 heads
        if (cfg[m].mask)
            gemm_nt<E_EXPM, 128><<<dim3(Nq / 128, Nk / 128, 4), 256, 0, stream>>>(
                bufQV, bufKV, Sbuf, nullptr, Nq, Nk, 128, 512, 512, Nk, sc1,
                128, 128, splane, NIL, 1, NIL, NIL);
        else
            gemm_nt<E_EXP, 128><<<dim3(Nq / 128, Nk / 128, 4), 256, 0, stream>>>(
                bufQV, bufKV, Sbuf, nullptr, Nq, Nk, 128, 512, 512, Nk, sc1,
                128, 128, splane, NIL, 1, NIL, NIL);
        // rdH[h][q] = 1/rowsum
        rowsum_inv_kernel<<<dim3(Nq, 4), 256, 0, stream>>>(Sbuf, rdH, Nk, splane, Nq);
        // expS^T for a2
        transpose_bf16_kernel<<<dim3(Nq / 64, Nk / 64, 4), 256, 0, stream>>>(Sbuf, PTbuf, Nq, Nk, splane);
        // VTs = qv^T with columns q scaled by rdH[h][q]
        scale_rows_kernel<<<512 * Nq / 2048, 256, 0, stream>>>(VTb, VTs, rdH, Nq, 7);
        // a1 partials: z = h*KZ1+kc, each (Nq x 128) = expS[h][:, kc*Kc1:...] @ kv^T[h]
        int KZ1 = (Nq == 2048) ? 4 : 2;  int Kc1 = Nk / KZ1;
        gemm_nt<E_PART, 128><<<dim3(Nq / 128, 1, 4 * KZ1), 256, 0, stream>>>(
            Sbuf, VTa, part, nullptr, Nq, 128, Kc1, Nk, Nk, 128, 0.f,
            splane, 128L * Nk, (long)Nq * 128, NIL, KZ1, Kc1, Kc1);
        reduce_kc_elu_kernel<<<Nq / 4, 256, 0, stream>>>(part, cfg[m].d1, Nq, KZ1, rdH);
        // a2 partials: z = h*KZ2+kc, each (Nk x 128) = expS^T[h][:, kc*Kc2:...] @ qv'^T[h]
        int KZ2 = (Nk == 2048) ? 4 : 2;  int Kc2 = Nq / KZ2;
        gemm_nt<E_PART, 128><<<dim3(Nk / 128, 1, 4 * KZ2), 256, 0, stream>>>(
            PTbuf, VTs, part, nullptr, Nk, 128, Kc2, Nq, Nq, 128, 0.f,
            splane, 128L * Nq, (long)Nk * 128, NIL, KZ2, Kc2, Kc2);
        reduce_kc_elu_kernel<<<Nk / 4, 256, 0, stream>>>(part, cfg[m].d2, Nk, KZ2, nullptr);
    }

    combine_obj_kernel<<<2048, 256, 0, stream>>>((const float4*)feat_obj, (const float4*)sub_obj,
        (const float4*)obj_sub, (const float4*)sub_rel, (const float4*)obj_rel,
        (float4*)out_obj, (ushort4*)bf_obj2);
    combine_rel1_kernel<<<4096, 256, 0, stream>>>((const float4*)feat_rel, (const float4*)rel_obj,
        (const float4*)rel_sub, (ushort4*)bf_rel2);

    const long spl2 = (long)4096 * 2048;   // stage-2 score plane
    const long vpl2 = (long)4096 * 512;    // stage-2 part plane

    // ---------------- stage 2 mha0: xq=obj2 (2048), xk=rel2 (4096); a2 only ----------------
    {
        transcvt_kernel<<<dim3(96, 32, 3), dim3(32, 8), 0, stream>>>(W_out, Wt2, 1024, 3072);
        // z=0 -> q (W0,b0), z=1 -> qv (W2,b2)
        gemm_nt<E_PROJ, 128><<<dim3(16, 24, 2), 256, 0, stream>>>(
            bf_obj2, Wt2, bufQV, b_out, 2048, 3072, 1024, 1024, 1024, 3072, 0.f,
            0, 2 * planeW2, (long)2048 * 3072, 2L * 3072, 1, NIL, NIL);
        gemm_nt<E_PROJ, 128><<<dim3(32, 24, 1), 256, 0, stream>>>(
            bf_rel2, Wt2 + planeW2, bufKV, b_out + 3072, 4096, 3072, 1024,
            1024, 1024, 3072, 0.f, 0, 0, 0, NIL, 1, NIL, NIL);
        transpose_bf16_kernel<<<dim3(32, 48, 1), 256, 0, stream>>>(
            bufQV + (size_t)2048 * 3072, VTa, 2048, 3072, 0);   // qv^T [3072][2048]
        // swapped scores: expS'[h][m_key][q] = exp(sc2 * K Q^T), 6 heads
        gemm_nt<E_EXP, 128><<<dim3(32, 16, 6), 256, 0, stream>>>(
            bufKV, bufQV, Sbuf, nullptr, 4096, 2048, 512, 3072, 3072, 2048, sc2,
            512, 512, spl2, NIL, 1, NIL, NIL);
        // rdQ[h][q] = 1/colsum(expS'[h])
        colsum_part_kernel<<<dim3(8, 16, 6), 256, 0, stream>>>(Sbuf, csP, 4096, 2048, 256, 16);
        colsum_fin_kernel<<<dim3(8, 6), 256, 0, stream>>>(csP, rdQ, 2048, 16);
        // VTs = qv^T with columns q scaled by rdQ[h][q] (dk=512 rows/head)
        scale_rows_kernel<<<3072 * 2048 / 2048, 256, 0, stream>>>(VTa, VTs, rdQ, 2048, 9);
        // part[h] = expS'[h] @ (scaled qv^T)[h]
        gemm_nt<E_PART, 128><<<dim3(32, 4, 6), 256, 0, stream>>>(
            Sbuf, VTs, part, nullptr, 4096, 512, 2048, 2048, 2048, 512, 0.f,
            spl2, 512L * 2048, vpl2, NIL, 1, NIL, NIL);
        reduce_h_elu_kernel<<<1024, 256, 0, stream>>>(part, rel_sub2, 4096, 6, nullptr);
    }
    // ---------------- stage 2 mha1: xq=rel2 (4096), xk=obj2 (2048); a1 only ----------------
    {
        transcvt_kernel<<<dim3(96, 32, 4), dim3(32, 8), 0, stream>>>(W_out + 4 * planeW2, Wt2, 1024, 3072);
        gemm_nt<E_PROJ, 128><<<dim3(32, 24, 1), 256, 0, stream>>>(
            bf_rel2, Wt2, bufQV, b_out + 4 * 3072, 4096, 3072, 1024,
            1024, 1024, 3072, 0.f, 0, 0, 0, NIL, 1, NIL, NIL);
        // z=0 -> k (W1,b1), z=1 -> kv (W3,b3)
        gemm_nt<E_PROJ, 128><<<dim3(16, 24, 2), 256, 0, stream>>>(
            bf_obj2, Wt2 + planeW2, bufKV, b_out + 5 * 3072, 2048, 3072, 1024,
            1024, 1024, 3072, 0.f, 0, 2 * planeW2, (long)2048 * 3072, 2L * 3072, 1, NIL, NIL);
        transpose_bf16_kernel<<<dim3(32, 48, 1), 256, 0, stream>>>(
            bufKV + (size_t)2048 * 3072, VTa, 2048, 3072, 0);   // kv^T [3072][2048]
        // scores: expS[h][q_rel][k_obj], 6 heads
        gemm_nt<E_EXP, 128><<<dim3(32, 16, 6), 256, 0, stream>>>(
            bufQV, bufKV, Sbuf, nullptr, 4096, 2048, 512, 3072, 3072, 2048, sc2,
            512, 512, spl2, NIL, 1, NIL, NIL);
        // rdM[h][row] = 1/rowsum
        rowsum_inv_kernel<<<dim3(4096, 6), 256, 0, stream>>>(Sbuf, rdM, 2048, spl2, 4096);
        // part[h] = expS[h] @ kv^T[h]; rd applied in reduce
        gemm_nt<E_PART, 128><<<dim3(32, 4, 6), 256, 0, stream>>>(
            Sbuf, VTa, part, nullptr, 4096, 512, 2048, 2048, 2048, 512, 0.f,
            spl2, 512L * 2048, vpl2, NIL, 1, NIL, NIL);
        reduce_h_elu_kernel<<<1024, 256, 0, stream>>>(part, rel_obj2, 4096, 6, rdM);
    }

    combine_rel2_kernel<<<4096, 256, 0, stream>>>((const float4*)feat_rel, (const float4*)rel_obj2,
        (const float4*)rel_sub2, (float4*)out_rel);
}

// Round 8
// 938.201 us; speedup vs baseline: 1.1309x; 1.0808x over previous
//
#include <hip/hip_runtime.h>

typedef unsigned short u16;
typedef unsigned int u32;
typedef __attribute__((ext_vector_type(4))) float f32x4;
typedef __attribute__((ext_vector_type(8))) __bf16 bf16x8;
typedef __attribute__((ext_vector_type(8))) unsigned short u16x8;

#if defined(__has_builtin)
#if __has_builtin(__builtin_amdgcn_global_load_lds)
#define HAS_GLL 1
#endif
#endif

__device__ __forceinline__ u16 f2bf(float f) {
    u32 u = __builtin_bit_cast(u32, f);
    u += 0x7fffu + ((u >> 16) & 1u);
    return (u16)(u >> 16);
}
__device__ __forceinline__ float bf2f(u16 x) {
    return __builtin_bit_cast(float, (u32)x << 16);
}

// counted-vmcnt barrier
template <int N> __device__ __forceinline__ void wbar() {
#ifdef HAS_GLL
    if constexpr (N == 0)
        asm volatile("s_waitcnt vmcnt(0)\n\ts_barrier" ::: "memory");
    else if constexpr (N == 2)
        asm volatile("s_waitcnt vmcnt(2)\n\ts_barrier" ::: "memory");
    else
        asm volatile("s_waitcnt vmcnt(4)\n\ts_barrier" ::: "memory");
#else
    __syncthreads();
#endif
}

// ---------------- utility kernels ----------------
__global__ __launch_bounds__(256) void zero_kernel(float* __restrict__ p, int n) {
    int i = blockIdx.x * 256 + threadIdx.x;
    if (i < n) p[i] = 0.f;
}

__global__ __launch_bounds__(256) void cvt_bf16_kernel(const float4* __restrict__ in,
                                                       ushort4* __restrict__ out, int n4) {
    int i = blockIdx.x * 256 + threadIdx.x;
    if (i < n4) {
        float4 v = in[i];
        ushort4 o;
        o.x = f2bf(v.x); o.y = f2bf(v.y); o.z = f2bf(v.z); o.w = f2bf(v.w);
        out[i] = o;
    }
}

// transpose + convert: W [B][K][N] f32 -> Wt [B][N][K] bf16
__global__ __launch_bounds__(256) void transcvt_kernel(const float* __restrict__ W,
                                                       u16* __restrict__ Wt, int K, int N) {
    __shared__ u16 t[32][33];
    int b = blockIdx.z;
    const float* Wb = W + (size_t)b * K * N;
    u16* Wtb = Wt + (size_t)b * K * N;
    int n0 = blockIdx.x * 32, k0 = blockIdx.y * 32;
    int tx = threadIdx.x, ty = threadIdx.y;
#pragma unroll
    for (int j = 0; j < 4; ++j)
        t[ty + j * 8][tx] = f2bf(Wb[(size_t)(k0 + ty + j * 8) * N + n0 + tx]);
    __syncthreads();
#pragma unroll
    for (int j = 0; j < 4; ++j)
        Wtb[(size_t)(n0 + ty + j * 8) * K + k0 + tx] = t[tx][ty + j * 8];
}

// ---------------- divide rows of [R][C] bf16 by sums[(r>>lg)*C + c] ----------------
__global__ __launch_bounds__(256) void scale_rows_kernel(const u16* __restrict__ in,
                                                         u16* __restrict__ out,
                                                         const float* __restrict__ rd,
                                                         int C, int lgdk) {
    int i = (blockIdx.x * 256 + threadIdx.x) * 8;
    int r = i / C, c = i % C;
    const float* rdp = rd + ((size_t)(r >> lgdk)) * C + c;
    u16x8 x = *reinterpret_cast<const u16x8*>(in + i);
    u16x8 o;
#pragma unroll
    for (int j = 0; j < 8; ++j) o[j] = f2bf(bf2f(x[j]) / rdp[j]);
    *reinterpret_cast<u16x8*>(out + i) = o;
}

// ---------------- GEMM: C = A (M,K) * B^T (N,K), row-major, 3-ring counted-vmcnt ----------------
// EPI variants: PROJ (bias, normal store) | PROJT (bias, transposed store only)
//   EXP (exp, normal, fused rowsum) | EXPC (exp, normal, fused colsum)
//   EXPT/EXPMT (exp [masked], normal + transposed stores, fused rowsum) | PART (raw bf16)
enum { E_PROJ = 0, E_PROJT, E_EXP, E_EXPC, E_EXPT, E_EXPMT, E_PART };

template <int EPI, int BM>
__global__ __launch_bounds__(256) void gemm_nt(const u16* __restrict__ A, const u16* __restrict__ B,
                                               void* __restrict__ Cv, void* __restrict__ CvT,
                                               const float* __restrict__ bias, float* __restrict__ rs,
                                               int M, int N, int K, int lda, int ldb, int ldc, int ldcT,
                                               float scale, long sAz, long sBz, long sCz, long sCzT,
                                               long sBias, long sRs, int ZK, long sAz2, long sBz2) {
    constexpr bool HAS_BIAS = (EPI == E_PROJ || EPI == E_PROJT);
    constexpr bool DO_EXP = (EPI == E_EXP || EPI == E_EXPC || EPI == E_EXPT || EPI == E_EXPMT);
    constexpr bool DO_MASK = (EPI == E_EXPMT);
    constexpr int RSUM = (EPI == E_EXPC) ? 2 : (DO_EXP ? 1 : 0);
    constexpr bool STORE_N = (EPI != E_PROJT);
    constexpr bool STORE_T = (EPI == E_PROJT || EPI == E_EXPT || EPI == E_EXPMT);

    constexpr int MF = BM / 32;
    constexpr int ITERS = BM * 32 / (256 * 8);
    constexpr int LOADS = ITERS * 2;
    constexpr int SM_STAGE = 3 * BM * 64;
    constexpr int SM_REPACK = BM * BM;
    __shared__ __align__(16) u16 smem[SM_STAGE > SM_REPACK ? SM_STAGE : SM_REPACK];
    const int tid = threadIdx.x;
    const int lane = tid & 63;
    const int wid = tid >> 6;
    const int wr = (wid >> 1) * (BM / 2);
    const int wc = (wid & 1) * (BM / 2);
    const int row0 = blockIdx.x * BM;
    const int col0 = blockIdx.y * BM;
    const long zo = blockIdx.z;
    const long hz = zo / ZK;
    const long kz = zo - hz * ZK;
    const u16* Az = A + hz * sAz + kz * sAz2;
    const u16* Bz = B + hz * sBz + kz * sBz2;
    const float* biasz = bias ? bias + zo * sBias : nullptr;
    float* rsz = rs ? rs + zo * sRs : nullptr;
    f32x4 acc[MF][MF] = {};

    auto As = [&](int buf) { return smem + buf * (BM * 64); };
    auto Bs = [&](int buf) { return smem + buf * (BM * 64) + BM * 32; };

    auto stage = [&](int buf, int k0) {
#pragma unroll
        for (int i = 0; i < ITERS; ++i) {
            int c = tid + i * 256;
            int r = c >> 2;
            int lch = (c & 3) ^ ((r >> 1) & 3);
            const u16* sa = Az + (size_t)(row0 + r) * lda + k0 + lch * 8;
            const u16* sb = Bz + (size_t)(col0 + r) * ldb + k0 + lch * 8;
#ifdef HAS_GLL
            __builtin_amdgcn_global_load_lds(
                (const __attribute__((address_space(1))) void*)sa,
                (__attribute__((address_space(3))) void*)(&As(buf)[c * 8]), 16, 0, 0);
            __builtin_amdgcn_global_load_lds(
                (const __attribute__((address_space(1))) void*)sb,
                (__attribute__((address_space(3))) void*)(&Bs(buf)[c * 8]), 16, 0, 0);
#else
            *reinterpret_cast<uint4*>(&As(buf)[c * 8]) = *reinterpret_cast<const uint4*>(sa);
            *reinterpret_cast<uint4*>(&Bs(buf)[c * 8]) = *reinterpret_cast<const uint4*>(sb);
#endif
        }
    };

    stage(0, 0);
    stage(1, 32);
    wbar<LOADS>();

    const int nsteps = K >> 5;
    for (int t = 0; t < nsteps; ++t) {
        const int bufc = t % 3;
        const bool more2 = (t + 2 < nsteps);
        if (more2) stage((t + 2) % 3, (t + 2) << 5);
        bf16x8 af[MF], bv[MF];
#pragma unroll
        for (int m = 0; m < MF; ++m) {
            int rr = wr + m * 16 + (lane & 15);
            int p = (lane >> 4) ^ ((rr >> 1) & 3);
            af[m] = *reinterpret_cast<const bf16x8*>(&As(bufc)[rr * 32 + p * 8]);
        }
#pragma unroll
        for (int n = 0; n < MF; ++n) {
            int rr = wc + n * 16 + (lane & 15);
            int p = (lane >> 4) ^ ((rr >> 1) & 3);
            bv[n] = *reinterpret_cast<const bf16x8*>(&Bs(bufc)[rr * 32 + p * 8]);
        }
#pragma unroll
        for (int m = 0; m < MF; ++m)
#pragma unroll
            for (int n = 0; n < MF; ++n)
                acc[m][n] = __builtin_amdgcn_mfma_f32_16x16x32_bf16(af[m], bv[n], acc[m][n], 0, 0, 0);
        if (more2)                 wbar<LOADS>();
        else if (t + 1 < nsteps)   wbar<0>();
        else                       __syncthreads();
    }

    // ---- math pass on accumulators ----
#pragma unroll
    for (int m = 0; m < MF; ++m) {
#pragma unroll
        for (int n = 0; n < MF; ++n) {
#pragma unroll
            for (int j = 0; j < 4; ++j) {
                float v = acc[m][n][j];
                if (HAS_BIAS) v += biasz[col0 + wc + n * 16 + (lane & 15)];
                if (DO_EXP) {
                    v = __expf(v * scale);
                    if (DO_MASK &&
                        row0 + wr + m * 16 + ((lane >> 4) << 2) + j ==
                        col0 + wc + n * 16 + (lane & 15)) v = 0.f;
                }
                acc[m][n][j] = v;
            }
        }
    }

    // ---- fused row/col sums (atomic partials) ----
    if (RSUM == 1) {
#pragma unroll
        for (int m = 0; m < MF; ++m) {
#pragma unroll
            for (int j = 0; j < 4; ++j) {
                float p = 0.f;
#pragma unroll
                for (int n = 0; n < MF; ++n) p += acc[m][n][j];
                p += __shfl_xor(p, 1); p += __shfl_xor(p, 2);
                p += __shfl_xor(p, 4); p += __shfl_xor(p, 8);
                if ((lane & 15) == 0)
                    atomicAdd(rsz + row0 + wr + m * 16 + ((lane >> 4) << 2) + j, p);
            }
        }
    } else if (RSUM == 2) {
#pragma unroll
        for (int n = 0; n < MF; ++n) {
            float p = 0.f;
#pragma unroll
            for (int m = 0; m < MF; ++m)
#pragma unroll
                for (int j = 0; j < 4; ++j) p += acc[m][n][j];
            p += __shfl_xor(p, 16); p += __shfl_xor(p, 32);
            if (lane < 16) atomicAdd(rsz + col0 + wc + n * 16 + lane, p);
        }
    }

    char* lc = reinterpret_cast<char*>(smem);
    // ---- normal store: swizzled repack + coalesced b128 ----
    if (STORE_N) {
#pragma unroll
        for (int m = 0; m < MF; ++m) {
#pragma unroll
            for (int n = 0; n < MF; ++n) {
#pragma unroll
                for (int j = 0; j < 4; ++j) {
                    int lrow = wr + m * 16 + ((lane >> 4) << 2) + j;
                    int lcol = wc + n * 16 + (lane & 15);
                    u32 byte = (u32)((lrow * BM + lcol) * 2) ^ (((lrow >> 2) & 3) << 5);
                    *reinterpret_cast<u16*>(lc + byte) = f2bf(acc[m][n][j]);
                }
            }
        }
        __syncthreads();
        constexpr int CH = BM / 8;
        constexpr int NIT = BM * CH / 256;
        u16* Cp = reinterpret_cast<u16*>(Cv) + zo * sCz;
#pragma unroll
        for (int it = 0; it < NIT; ++it) {
            int idx = it * 256 + tid;
            int rrow = idx / CH, c8 = idx % CH;
            u32 byte = (u32)((rrow * BM + c8 * 8) * 2) ^ (((rrow >> 2) & 3) << 5);
            u16x8 val = *reinterpret_cast<const u16x8*>(lc + byte);
            *reinterpret_cast<u16x8*>(Cp + (size_t)(row0 + rrow) * ldc + col0 + c8 * 8) = val;
        }
    }
    // ---- transposed store: b64 column writes (swizzled) + coalesced b128 ----
    if (STORE_T) {
        __syncthreads();
#pragma unroll
        for (int m = 0; m < MF; ++m) {
#pragma unroll
            for (int n = 0; n < MF; ++n) {
                int lcol = wc + n * 16 + (lane & 15);
                int lrow0 = wr + m * 16 + ((lane >> 4) << 2);
                u32 byte = (u32)((lcol * BM + lrow0) * 2) ^ ((u32)(lcol & 7) << 4);
                u32 lo = (u32)f2bf(acc[m][n][0]) | ((u32)f2bf(acc[m][n][1]) << 16);
                u32 hi = (u32)f2bf(acc[m][n][2]) | ((u32)f2bf(acc[m][n][3]) << 16);
                uint2 pk; pk.x = lo; pk.y = hi;
                *reinterpret_cast<uint2*>(lc + byte) = pk;
            }
        }
        __syncthreads();
        constexpr int CHT = BM / 8;
        constexpr int NITT = BM * CHT / 256;
        u16* Tp = reinterpret_cast<u16*>(CvT) + zo * sCzT;
#pragma unroll
        for (int it = 0; it < NITT; ++it) {
            int idx = it * 256 + tid;
            int c = idx / CHT, r8 = idx % CHT;
            u32 byte = (u32)((c * BM + r8 * 8) * 2) ^ ((u32)(c & 7) << 4);
            u16x8 val = *reinterpret_cast<const u16x8*>(lc + byte);
            *reinterpret_cast<u16x8*>(Tp + (size_t)(col0 + c) * ldcT + row0 + r8 * 8) = val;
        }
    }
}

// ---------------- stage-1 reduce: out[row][h*128+d] = elu((1/rd_h[row]) * sum_kc part[h,kc]) ----------------
__global__ __launch_bounds__(256) void reduce_kc_elu_kernel(const u16* __restrict__ part,
                                                            float* __restrict__ out, int M, int KZ,
                                                            const float* __restrict__ rd) {
    int i = blockIdx.x * 256 + threadIdx.x;
    int row = i >> 6;
    int hc = i & 63;
    int h = hc >> 4, c8 = hc & 15;
    long plane = (long)M * 128;
    const u16* p = part + (size_t)(h * KZ) * plane + (size_t)row * 128 + c8 * 8;
    float s[8] = {};
    for (int kc = 0; kc < KZ; ++kc) {
        u16x8 x = *reinterpret_cast<const u16x8*>(p + (size_t)kc * plane);
#pragma unroll
        for (int j = 0; j < 8; ++j) s[j] += bf2f(x[j]);
    }
    float r = rd ? 1.f / rd[(size_t)h * M + row] : 1.f;
#pragma unroll
    for (int j = 0; j < 8; ++j) {
        float v = s[j] * r;
        s[j] = v > 0.f ? v : (__expf(v) - 1.f);
    }
    float4* o = reinterpret_cast<float4*>(out + (size_t)row * 512 + h * 128 + c8 * 8);
    o[0] = float4{s[0], s[1], s[2], s[3]};
    o[1] = float4{s[4], s[5], s[6], s[7]};
}

// ---------------- stage-2 reduce: out[row][d] = sum_h elu((1/rd_h[row]) * part[h][row][d]) ----------------
__global__ __launch_bounds__(256) void reduce_h_elu_kernel(const u16* __restrict__ part,
                                                           float* __restrict__ out, int R, int H,
                                                           const float* __restrict__ rd) {
    int i = blockIdx.x * 256 + threadIdx.x;
    int row = i >> 6, c8 = i & 63;
    long plane = (long)R * 512;
    const u16* p = part + (size_t)row * 512 + c8 * 8;
    float s[8] = {};
    for (int h = 0; h < H; ++h) {
        u16x8 x = *reinterpret_cast<const u16x8*>(p + (size_t)h * plane);
        float r = rd ? 1.f / rd[(size_t)h * R + row] : 1.f;
#pragma unroll
        for (int j = 0; j < 8; ++j) {
            float v = bf2f(x[j]) * r;
            s[j] += v > 0.f ? v : (__expf(v) - 1.f);
        }
    }
    float4* o = reinterpret_cast<float4*>(out + (size_t)row * 512 + c8 * 8);
    o[0] = float4{s[0], s[1], s[2], s[3]};
    o[1] = float4{s[4], s[5], s[6], s[7]};
}

// ---------------- combines (float4) ----------------
__global__ __launch_bounds__(256) void combine_obj_kernel(const float4* __restrict__ feat,
        const float4* __restrict__ a, const float4* __restrict__ b,
        const float4* __restrict__ c, const float4* __restrict__ d,
        float4* __restrict__ out, ushort4* __restrict__ outbf) {
    int i = blockIdx.x * 256 + threadIdx.x;
    int r = i >> 8, c4 = i & 255;
    size_t half = (size_t)r * 128 + (c4 & 127);
    float4 t1 = (c4 < 128) ? a[half] : b[half];
    float4 t2 = (c4 < 128) ? c[half] : d[half];
    float4 f = feat[i];
    float4 o;
    o.x = (f.x + t1.x + t2.x) * (1.f / 3.f);
    o.y = (f.y + t1.y + t2.y) * (1.f / 3.f);
    o.z = (f.z + t1.z + t2.z) * (1.f / 3.f);
    o.w = (f.w + t1.w + t2.w) * (1.f / 3.f);
    out[i] = o;
    ushort4 ob; ob.x = f2bf(o.x); ob.y = f2bf(o.y); ob.z = f2bf(o.z); ob.w = f2bf(o.w);
    outbf[i] = ob;
}

__global__ __launch_bounds__(256) void combine_rel1_kernel(const float4* __restrict__ feat,
        const float4* __restrict__ a, const float4* __restrict__ b, ushort4* __restrict__ outbf) {
    int i = blockIdx.x * 256 + threadIdx.x;
    int r = i >> 8, c4 = i & 255;
    size_t half = (size_t)r * 128 + (c4 & 127);
    float4 t = (c4 < 128) ? a[half] : b[half];
    float4 f = feat[i];
    ushort4 ob;
    ob.x = f2bf((f.x + t.x) * 0.5f); ob.y = f2bf((f.y + t.y) * 0.5f);
    ob.z = f2bf((f.z + t.z) * 0.5f); ob.w = f2bf((f.w + t.w) * 0.5f);
    outbf[i] = ob;
}

__global__ __launch_bounds__(256) void combine_rel2_kernel(const float4* __restrict__ feat,
        const float4* __restrict__ a, const float4* __restrict__ b, float4* __restrict__ out) {
    int i = blockIdx.x * 256 + threadIdx.x;
    int r = i >> 8, c4 = i & 255;
    size_t half = (size_t)r * 128 + (c4 & 127);
    float4 t = (c4 < 128) ? a[half] : b[half];
    float4 f = feat[i];
    float4 o;
    o.x = (f.x + t.x) * 0.5f; o.y = (f.y + t.y) * 0.5f;
    o.z = (f.z + t.z) * 0.5f; o.w = (f.w + t.w) * 0.5f;
    out[i] = o;
}

extern "C" void kernel_launch(void* const* d_in, const int* in_sizes, int n_in,
                              void* d_out, int out_size, void* d_ws, size_t ws_size,
                              hipStream_t stream) {
    (void)in_sizes; (void)n_in; (void)out_size; (void)ws_size;
    const float* feat_obj = (const float*)d_in[0];
    const float* feat_rel = (const float*)d_in[1];
    const float* W_cat = (const float*)d_in[2];
    const float* b_cat = (const float*)d_in[3];
    const float* W_out = (const float*)d_in[4];
    const float* b_out = (const float*)d_in[5];
    float* out_obj = (float*)d_out;
    float* out_rel = (float*)d_out + (size_t)2048 * 1024;

    char* w = (char*)d_ws;
    auto alloc = [&](size_t bytes) { void* p = (void*)w; w += (bytes + 255) & ~(size_t)255; return p; };
    u16* bf_obj  = (u16*)alloc((size_t)2048 * 1024 * 2);
    u16* bf_rel  = (u16*)alloc((size_t)4096 * 1024 * 2);
    u16* bf_obj2 = (u16*)alloc((size_t)2048 * 1024 * 2);
    u16* bf_rel2 = (u16*)alloc((size_t)4096 * 1024 * 2);
    u16* Wt_cat  = (u16*)alloc((size_t)12 * 512 * 1024 * 2);
    u16* Wt2     = (u16*)alloc((size_t)4 * 3072 * 1024 * 2);
    u16* bufQV   = (u16*)alloc((size_t)4096 * 3072 * 2);       // q plane
    u16* bufKV   = (u16*)alloc((size_t)4096 * 3072 * 2);       // k plane
    u16* VTa     = (u16*)alloc((size_t)3072 * 2048 * 2);       // kv^T / qv^T (stage2)
    u16* VTb     = (u16*)alloc((size_t)512 * 4096 * 2);        // qv^T (stage1)
    u16* VTs     = (u16*)alloc((size_t)3072 * 2048 * 2);       // scaled V^T
    u16* Sbuf    = (u16*)alloc((size_t)6 * 4096 * 2048 * 2);   // expS planes
    u16* PTbuf   = (u16*)alloc((size_t)4 * 2048 * 4096 * 2);   // stage1 expS^T planes
    u16* part    = (u16*)alloc((size_t)6 * 4096 * 512 * 2);
    float* rdAll = (float*)alloc((size_t)69632 * 4);
    float* rdH0 = rdAll;              // 4*2048
    float* rdH1 = rdAll + 8192;       // 4*2048
    float* rdH2 = rdAll + 16384;      // 4*4096
    float* rdQ  = rdAll + 32768;      // 6*2048
    float* rdM  = rdAll + 45056;      // 6*4096
    float* sub_obj  = (float*)alloc((size_t)2048 * 512 * 4);
    float* obj_sub  = (float*)alloc((size_t)2048 * 512 * 4);
    float* sub_rel  = (float*)alloc((size_t)2048 * 512 * 4);
    float* obj_rel  = (float*)alloc((size_t)2048 * 512 * 4);
    float* rel_obj  = (float*)alloc((size_t)4096 * 512 * 4);
    float* rel_sub  = (float*)alloc((size_t)4096 * 512 * 4);
    float* rel_obj2 = (float*)alloc((size_t)4096 * 512 * 4);
    float* rel_sub2 = (float*)alloc((size_t)4096 * 512 * 4);

    zero_kernel<<<(69632 + 255) / 256, 256, 0, stream>>>(rdAll, 69632);
    cvt_bf16_kernel<<<2048, 256, 0, stream>>>((const float4*)feat_obj, (ushort4*)bf_obj, 2048 * 1024 / 4);
    cvt_bf16_kernel<<<4096, 256, 0, stream>>>((const float4*)feat_rel, (ushort4*)bf_rel, 4096 * 1024 / 4);
    transcvt_kernel<<<dim3(16, 32, 12), dim3(32, 8), 0, stream>>>(W_cat, Wt_cat, 1024, 512);

    const float sc1 = 0.08838834764831845f;  // 1/sqrt(128)
    const float sc2 = 0.04419417382415922f;  // 1/sqrt(512)
    const long planeW = (long)512 * 1024;
    const long planeW2 = (long)3072 * 1024;
    const long NIL = 0;

    // ---------------- stage 1: three concat=True MHAs, h=4, d_k=128 ----------------
    struct MhaCfg { const u16* xq; const u16* xk; int Nq, Nk; float* d1; float* d2; float* rd; int mask; };
    MhaCfg cfg[3] = {
        { bf_obj, bf_obj, 2048, 2048, sub_obj, obj_sub, rdH0, 1 },
        { bf_obj, bf_rel, 2048, 4096, sub_rel, rel_sub, rdH1, 0 },
        { bf_rel, bf_obj, 4096, 2048, rel_obj, obj_rel, rdH2, 0 },
    };
    for (int m = 0; m < 3; ++m) {
        const u16* Wt = Wt_cat + (size_t)m * 4 * planeW;
        const float* bb = b_cat + m * 4 * 512;
        int Nq = cfg[m].Nq, Nk = cfg[m].Nk;
        long splane = (long)Nq * Nk;
        // q, k projections (normal layout)
        gemm_nt<E_PROJ, 64><<<dim3(Nq / 64, 8, 1), 256, 0, stream>>>(
            cfg[m].xq, Wt, bufQV, nullptr, bb, nullptr,
            Nq, 512, 1024, 1024, 1024, 512, 0, 0.f, NIL, NIL, NIL, NIL, NIL, NIL, 1, NIL, NIL);
        gemm_nt<E_PROJ, 64><<<dim3(Nk / 64, 8, 1), 256, 0, stream>>>(
            cfg[m].xk, Wt + planeW, bufKV, nullptr, bb + 512, nullptr,
            Nk, 512, 1024, 1024, 1024, 512, 0, 0.f, NIL, NIL, NIL, NIL, NIL, NIL, 1, NIL, NIL);
        // qv^T, kv^T projections (transposed store only)
        gemm_nt<E_PROJT, 64><<<dim3(Nq / 64, 8, 1), 256, 0, stream>>>(
            cfg[m].xq, Wt + 2 * planeW, nullptr, VTb, bb + 1024, nullptr,
            Nq, 512, 1024, 1024, 1024, 0, Nq, 0.f, NIL, NIL, NIL, NIL, NIL, NIL, 1, NIL, NIL);
        gemm_nt<E_PROJT, 64><<<dim3(Nk / 64, 8, 1), 256, 0, stream>>>(
            cfg[m].xk, Wt + 3 * planeW, nullptr, VTa, bb + 1536, nullptr,
            Nk, 512, 1024, 1024, 1024, 0, Nk, 0.f, NIL, NIL, NIL, NIL, NIL, NIL, 1, NIL, NIL);
        // expS (normal + transposed) + fused rowsum, 4 heads
        if (cfg[m].mask)
            gemm_nt<E_EXPMT, 128><<<dim3(Nq / 128, Nk / 128, 4), 256, 0, stream>>>(
                bufQV, bufKV, Sbuf, PTbuf, nullptr, cfg[m].rd,
                Nq, Nk, 128, 512, 512, Nk, Nq, sc1, 128, 128, splane, splane, NIL, Nq, 1, NIL, NIL);
        else
            gemm_nt<E_EXPT, 128><<<dim3(Nq / 128, Nk / 128, 4), 256, 0, stream>>>(
                bufQV, bufKV, Sbuf, PTbuf, nullptr, cfg[m].rd,
                Nq, Nk, 128, 512, 512, Nk, Nq, sc1, 128, 128, splane, splane, NIL, Nq, 1, NIL, NIL);
        // VTs = qv^T / rowsum (columns q scaled)
        scale_rows_kernel<<<512 * Nq / 2048, 256, 0, stream>>>(VTb, VTs, cfg[m].rd, Nq, 7);
        // a1 partials: z = h*KZ1+kc
        int KZ1 = (Nq == 2048) ? 4 : 2;  int Kc1 = Nk / KZ1;
        gemm_nt<E_PART, 128><<<dim3(Nq / 128, 1, 4 * KZ1), 256, 0, stream>>>(
            Sbuf, VTa, part, nullptr, nullptr, nullptr,
            Nq, 128, Kc1, Nk, Nk, 128, 0, 0.f, splane, 128L * Nk, (long)Nq * 128, NIL, NIL, NIL,
            KZ1, Kc1, Kc1);
        reduce_kc_elu_kernel<<<Nq / 4, 256, 0, stream>>>(part, cfg[m].d1, Nq, KZ1, cfg[m].rd);
        // a2 partials: z = h*KZ2+kc
        int KZ2 = (Nk == 2048) ? 4 : 2;  int Kc2 = Nq / KZ2;
        gemm_nt<E_PART, 128><<<dim3(Nk / 128, 1, 4 * KZ2), 256, 0, stream>>>(
            PTbuf, VTs, part, nullptr, nullptr, nullptr,
            Nk, 128, Kc2, Nq, Nq, 128, 0, 0.f, splane, 128L * Nq, (long)Nk * 128, NIL, NIL, NIL,
            KZ2, Kc2, Kc2);
        reduce_kc_elu_kernel<<<Nk / 4, 256, 0, stream>>>(part, cfg[m].d2, Nk, KZ2, nullptr);
    }

    combine_obj_kernel<<<2048, 256, 0, stream>>>((const float4*)feat_obj, (const float4*)sub_obj,
        (const float4*)obj_sub, (const float4*)sub_rel, (const float4*)obj_rel,
        (float4*)out_obj, (ushort4*)bf_obj2);
    combine_rel1_kernel<<<4096, 256, 0, stream>>>((const float4*)feat_rel, (const float4*)rel_obj,
        (const float4*)rel_sub, (ushort4*)bf_rel2);

    const long spl2 = (long)4096 * 2048;
    const long vpl2 = (long)4096 * 512;

    // ---------------- stage 2 mha0: xq=obj2 (2048), xk=rel2 (4096); a2 only ----------------
    {
        transcvt_kernel<<<dim3(96, 32, 3), dim3(32, 8), 0, stream>>>(W_out, Wt2, 1024, 3072);
        gemm_nt<E_PROJ, 128><<<dim3(16, 24, 1), 256, 0, stream>>>(
            bf_obj2, Wt2, bufQV, nullptr, b_out, nullptr,
            2048, 3072, 1024, 1024, 1024, 3072, 0, 0.f, NIL, NIL, NIL, NIL, NIL, NIL, 1, NIL, NIL);
        gemm_nt<E_PROJ, 128><<<dim3(32, 24, 1), 256, 0, stream>>>(
            bf_rel2, Wt2 + planeW2, bufKV, nullptr, b_out + 3072, nullptr,
            4096, 3072, 1024, 1024, 1024, 3072, 0, 0.f, NIL, NIL, NIL, NIL, NIL, NIL, 1, NIL, NIL);
        gemm_nt<E_PROJT, 128><<<dim3(16, 24, 1), 256, 0, stream>>>(
            bf_obj2, Wt2 + 2 * planeW2, nullptr, VTa, b_out + 2 * 3072, nullptr,
            2048, 3072, 1024, 1024, 1024, 0, 2048, 0.f, NIL, NIL, NIL, NIL, NIL, NIL, 1, NIL, NIL);
        // swapped scores expS'[h][m_key][q] + fused colsum -> rdQ
        gemm_nt<E_EXPC, 128><<<dim3(32, 16, 6), 256, 0, stream>>>(
            bufKV, bufQV, Sbuf, nullptr, nullptr, rdQ,
            4096, 2048, 512, 3072, 3072, 2048, 0, sc2, 512, 512, spl2, NIL, NIL, 2048, 1, NIL, NIL);
        // VTs = qv^T / colsum
        scale_rows_kernel<<<3072 * 2048 / 2048, 256, 0, stream>>>(VTa, VTs, rdQ, 2048, 9);
        gemm_nt<E_PART, 128><<<dim3(32, 4, 6), 256, 0, stream>>>(
            Sbuf, VTs, part, nullptr, nullptr, nullptr,
            4096, 512, 2048, 2048, 2048, 512, 0, 0.f, spl2, 512L * 2048, vpl2, NIL, NIL, NIL,
            1, NIL, NIL);
        reduce_h_elu_kernel<<<1024, 256, 0, stream>>>(part, rel_sub2, 4096, 6, nullptr);
    }
    // ---------------- stage 2 mha1: xq=rel2 (4096), xk=obj2 (2048); a1 only ----------------
    {
        transcvt_kernel<<<dim3(96, 32, 4), dim3(32, 8), 0, stream>>>(W_out + 4 * planeW2, Wt2, 1024, 3072);
        gemm_nt<E_PROJ, 128><<<dim3(32, 24, 1), 256, 0, stream>>>(
            bf_rel2, Wt2, bufQV, nullptr, b_out + 4 * 3072, nullptr,
            4096, 3072, 1024, 1024, 1024, 3072, 0, 0.f, NIL, NIL, NIL, NIL, NIL, NIL, 1, NIL, NIL);
        gemm_nt<E_PROJ, 128><<<dim3(16, 24, 1), 256, 0, stream>>>(
            bf_obj2, Wt2 + planeW2, bufKV, nullptr, b_out + 5 * 3072, nullptr,
            2048, 3072, 1024, 1024, 1024, 3072, 0, 0.f, NIL, NIL, NIL, NIL, NIL, NIL, 1, NIL, NIL);
        gemm_nt<E_PROJT, 128><<<dim3(16, 24, 1), 256, 0, stream>>>(
            bf_obj2, Wt2 + 3 * planeW2, nullptr, VTa, b_out + 7 * 3072, nullptr,
            2048, 3072, 1024, 1024, 1024, 0, 2048, 0.f, NIL, NIL, NIL, NIL, NIL, NIL, 1, NIL, NIL);
        // scores expS[h][q_rel][k_obj] + fused rowsum -> rdM
        gemm_nt<E_EXP, 128><<<dim3(32, 16, 6), 256, 0, stream>>>(
            bufQV, bufKV, Sbuf, nullptr, nullptr, rdM,
            4096, 2048, 512, 3072, 3072, 2048, 0, sc2, 512, 512, spl2, NIL, NIL, 4096, 1, NIL, NIL);
        gemm_nt<E_PART, 128><<<dim3(32, 4, 6), 256, 0, stream>>>(
            Sbuf, VTa, part, nullptr, nullptr, nullptr,
            4096, 512, 2048, 2048, 2048, 512, 0, 0.f, spl2, 512L * 2048, vpl2, NIL, NIL, NIL,
            1, NIL, NIL);
        reduce_h_elu_kernel<<<1024, 256, 0, stream>>>(part, rel_obj2, 4096, 6, rdM);
    }

    combine_rel2_kernel<<<4096, 256, 0, stream>>>((const float4*)feat_rel, (const float4*)rel_obj2,
        (const float4*)rel_sub2, (float4*)out_rel);
}

// Round 10
// 813.537 us; speedup vs baseline: 1.3042x; 1.1532x over previous
//
#include <hip/hip_runtime.h>

typedef unsigned short u16;
typedef unsigned int u32;
typedef __attribute__((ext_vector_type(4))) float f32x4;
typedef __attribute__((ext_vector_type(8))) __bf16 bf16x8;
typedef __attribute__((ext_vector_type(8))) unsigned short u16x8;

#if defined(__has_builtin)
#if __has_builtin(__builtin_amdgcn_global_load_lds)
#define HAS_GLL 1
#endif
#endif

__device__ __forceinline__ u16 f2bf(float f) {
    u32 u = __builtin_bit_cast(u32, f);
    u += 0x7fffu + ((u >> 16) & 1u);
    return (u16)(u >> 16);
}
__device__ __forceinline__ float bf2f(u16 x) {
    return __builtin_bit_cast(float, (u32)x << 16);
}

// counted-vmcnt barrier
template <int N> __device__ __forceinline__ void wbar() {
#ifdef HAS_GLL
    if constexpr (N == 0)
        asm volatile("s_waitcnt vmcnt(0)\n\ts_barrier" ::: "memory");
    else if constexpr (N == 2)
        asm volatile("s_waitcnt vmcnt(2)\n\ts_barrier" ::: "memory");
    else
        asm volatile("s_waitcnt vmcnt(4)\n\ts_barrier" ::: "memory");
#else
    __syncthreads();
#endif
}

// full drain barrier (vm + lgkm) for producer/consumer LDS phases
__device__ __forceinline__ void fbar() {
#ifdef HAS_GLL
    asm volatile("s_waitcnt vmcnt(0) lgkmcnt(0)\n\ts_barrier" ::: "memory");
#else
    __syncthreads();
#endif
}

// ---------------- utility kernels ----------------
__global__ __launch_bounds__(256) void zero_kernel(float* __restrict__ p, int n) {
    int i = blockIdx.x * 256 + threadIdx.x;
    if (i < n) p[i] = 0.f;
}

__global__ __launch_bounds__(256) void cvt_bf16_kernel(const float4* __restrict__ in,
                                                       ushort4* __restrict__ out, int n4) {
    int i = blockIdx.x * 256 + threadIdx.x;
    if (i < n4) {
        float4 v = in[i];
        ushort4 o;
        o.x = f2bf(v.x); o.y = f2bf(v.y); o.z = f2bf(v.z); o.w = f2bf(v.w);
        out[i] = o;
    }
}

// transpose + convert: W [B][K][N] f32 -> Wt [B][N][K] bf16
__global__ __launch_bounds__(256) void transcvt_kernel(const float* __restrict__ W,
                                                       u16* __restrict__ Wt, int K, int N) {
    __shared__ u16 t[32][33];
    int b = blockIdx.z;
    const float* Wb = W + (size_t)b * K * N;
    u16* Wtb = Wt + (size_t)b * K * N;
    int n0 = blockIdx.x * 32, k0 = blockIdx.y * 32;
    int tx = threadIdx.x, ty = threadIdx.y;
#pragma unroll
    for (int j = 0; j < 4; ++j)
        t[ty + j * 8][tx] = f2bf(Wb[(size_t)(k0 + ty + j * 8) * N + n0 + tx]);
    __syncthreads();
#pragma unroll
    for (int j = 0; j < 4; ++j)
        Wtb[(size_t)(n0 + ty + j * 8) * K + k0 + tx] = t[tx][ty + j * 8];
}

// ---------------- divide rows of [R][C] bf16 by sums[(r>>lg)*C + c] ----------------
__global__ __launch_bounds__(256) void scale_rows_kernel(const u16* __restrict__ in,
                                                         u16* __restrict__ out,
                                                         const float* __restrict__ rd,
                                                         int C, int lgdk) {
    int i = (blockIdx.x * 256 + threadIdx.x) * 8;
    int r = i / C, c = i % C;
    const float* rdp = rd + ((size_t)(r >> lgdk)) * C + c;
    u16x8 x = *reinterpret_cast<const u16x8*>(in + i);
    u16x8 o;
#pragma unroll
    for (int j = 0; j < 8; ++j) o[j] = f2bf(bf2f(x[j]) / rdp[j]);
    *reinterpret_cast<u16x8*>(out + i) = o;
}

// ---------------- fused stage-1 attention ----------------
// Per z-plane (group g = z>>2, head h = z&3), per 64-row tile:
//   loop key tiles of 64: S = exp(scale * A K^T) [masked diag], rowsum accum,
//   P -> LDS (staging layout), out += P @ V^T. Final: out = elu(out / rowsum).
struct FGrp { const u16* A; const u16* B; const u16* V; float* O; int M; int NK; int mask; };
struct FCfg { FGrp g[6]; };

__global__ __launch_bounds__(256) void fused_attn1_kernel(FCfg cfg, float scale) {
    __shared__ __align__(16) u16 Abuf[4 * 2048];   // [kb][64 rows][32 dk]
    __shared__ __align__(16) u16 Bbuf[4 * 2048];   // [kb][64 keys][32 dk]
    __shared__ __align__(16) u16 Vbuf[2 * 4096];   // [kb][128 d][32 keys]
    __shared__ __align__(16) u16 Pbuf[2 * 2048];   // [kb][64 rows][32 keys]
    __shared__ float rsum_lds[64][2];
    const int gi = blockIdx.z >> 2, h = blockIdx.z & 3;
    FGrp G;
    switch (gi) {
        case 0: G = cfg.g[0]; break;
        case 1: G = cfg.g[1]; break;
        case 2: G = cfg.g[2]; break;
        case 3: G = cfg.g[3]; break;
        case 4: G = cfg.g[4]; break;
        default: G = cfg.g[5]; break;
    }
    const int row0 = blockIdx.x * 64;
    if (row0 >= G.M) return;
    const u16* Ap = G.A + h * 128;                     // lda 512
    const u16* Bp = G.B + h * 128;                     // ldb 512
    const u16* Vp = G.V + (size_t)h * 128 * G.NK;      // ldv NK
    float* Op = G.O + h * 128;                         // ldo 512
    const int ldv = G.NK;
    const int tid = threadIdx.x, lane = tid & 63, wid = tid >> 6;
    const int swr = (wid >> 1) * 32, swc = (wid & 1) * 32;
    const int pwr = swr, pwc = (wid & 1) * 64;

    auto gld = [&](const u16* src, u16* dst) {
#ifdef HAS_GLL
        __builtin_amdgcn_global_load_lds(
            (const __attribute__((address_space(1))) void*)src,
            (__attribute__((address_space(3))) void*)dst, 16, 0, 0);
#else
        *reinterpret_cast<uint4*>(dst) = *reinterpret_cast<const uint4*>(src);
#endif
    };
    auto stageB = [&](int t) {
#pragma unroll
        for (int it = 0; it < 4; ++it) {
            int c = tid + it * 256;
            int kb = c >> 8, cc = c & 255;
            int r = cc >> 2, lch = (cc & 3) ^ ((r >> 1) & 3);
            gld(Bp + (size_t)(t * 64 + r) * 512 + kb * 32 + lch * 8, &Bbuf[kb * 2048 + cc * 8]);
        }
    };
    auto stageV = [&](int t) {
#pragma unroll
        for (int it = 0; it < 4; ++it) {
            int c = tid + it * 256;
            int kb = c >> 9, cc = c & 511;
            int r = cc >> 2, lch = (cc & 3) ^ ((r >> 1) & 3);
            gld(Vp + (size_t)r * ldv + t * 64 + kb * 32 + lch * 8, &Vbuf[kb * 4096 + cc * 8]);
        }
    };

    // stage A tile (rows x 128 dk) once
#pragma unroll
    for (int it = 0; it < 4; ++it) {
        int c = tid + it * 256;
        int kb = c >> 8, cc = c & 255;
        int r = cc >> 2, lch = (cc & 3) ^ ((r >> 1) & 3);
        gld(Ap + (size_t)(row0 + r) * 512 + kb * 32 + lch * 8, &Abuf[kb * 2048 + cc * 8]);
    }
    stageB(0);
    fbar();

    f32x4 accp[2][4] = {};
    float rsum[2][4] = {};
    const int nt = G.NK >> 6;
    for (int t = 0; t < nt; ++t) {
        stageV(t);
        // ---- S phase: 64 rows x 64 keys, dk = 128 ----
        f32x4 accs[2][2] = {};
#pragma unroll
        for (int kk = 0; kk < 4; ++kk) {
            bf16x8 af[2], bf[2];
#pragma unroll
            for (int m = 0; m < 2; ++m) {
                int rr = swr + m * 16 + (lane & 15);
                int p = (lane >> 4) ^ ((rr >> 1) & 3);
                af[m] = *reinterpret_cast<const bf16x8*>(&Abuf[kk * 2048 + rr * 32 + p * 8]);
            }
#pragma unroll
            for (int n = 0; n < 2; ++n) {
                int rr = swc + n * 16 + (lane & 15);
                int p = (lane >> 4) ^ ((rr >> 1) & 3);
                bf[n] = *reinterpret_cast<const bf16x8*>(&Bbuf[kk * 2048 + rr * 32 + p * 8]);
            }
#pragma unroll
            for (int m = 0; m < 2; ++m)
#pragma unroll
                for (int n = 0; n < 2; ++n)
                    accs[m][n] = __builtin_amdgcn_mfma_f32_16x16x32_bf16(af[m], bf[n], accs[m][n], 0, 0, 0);
        }
        // ---- exp + rowsum + P write (staging layout, chunk-XOR) ----
#pragma unroll
        for (int m = 0; m < 2; ++m) {
#pragma unroll
            for (int n = 0; n < 2; ++n) {
#pragma unroll
                for (int j = 0; j < 4; ++j) {
                    int prow = swr + m * 16 + ((lane >> 4) << 2) + j;
                    int pkey = swc + n * 16 + (lane & 15);
                    float v = __expf(accs[m][n][j] * scale);
                    if (G.mask && (row0 + prow == t * 64 + pkey)) v = 0.f;
                    rsum[m][j] += v;
                    Pbuf[(pkey >> 5) * 2048 + prow * 32 +
                         ((((pkey >> 3) & 3) ^ ((prow >> 1) & 3)) << 3) + (pkey & 7)] = f2bf(v);
                }
            }
        }
        fbar();                     // V(t) arrived; P visible to all waves
        if (t + 1 < nt) stageB(t + 1);
        // ---- PV phase: out 64 rows x 128 d, contraction 64 keys ----
#pragma unroll
        for (int kk = 0; kk < 2; ++kk) {
            bf16x8 pf[2], vf[4];
#pragma unroll
            for (int m = 0; m < 2; ++m) {
                int rr = pwr + m * 16 + (lane & 15);
                int p = (lane >> 4) ^ ((rr >> 1) & 3);
                pf[m] = *reinterpret_cast<const bf16x8*>(&Pbuf[kk * 2048 + rr * 32 + p * 8]);
            }
#pragma unroll
            for (int n = 0; n < 4; ++n) {
                int dd = pwc + n * 16 + (lane & 15);
                int p = (lane >> 4) ^ ((dd >> 1) & 3);
                vf[n] = *reinterpret_cast<const bf16x8*>(&Vbuf[kk * 4096 + dd * 32 + p * 8]);
            }
#pragma unroll
            for (int m = 0; m < 2; ++m)
#pragma unroll
                for (int n = 0; n < 4; ++n)
                    accp[m][n] = __builtin_amdgcn_mfma_f32_16x16x32_bf16(pf[m], vf[n], accp[m][n], 0, 0, 0);
        }
        fbar();                     // B(t+1) arrived; P/V reads retired
    }

    // ---- rowsum merge across the 2 key-slice waves ----
#pragma unroll
    for (int m = 0; m < 2; ++m)
#pragma unroll
        for (int j = 0; j < 4; ++j) {
            float s = rsum[m][j];
            s += __shfl_xor(s, 1); s += __shfl_xor(s, 2);
            s += __shfl_xor(s, 4); s += __shfl_xor(s, 8);
            rsum[m][j] = s;
        }
    if ((lane & 15) == 0) {
#pragma unroll
        for (int m = 0; m < 2; ++m)
#pragma unroll
            for (int j = 0; j < 4; ++j)
                rsum_lds[swr + m * 16 + ((lane >> 4) << 2) + j][wid & 1] = rsum[m][j];
    }
    __syncthreads();
    // ---- scale + ELU + store ----
#pragma unroll
    for (int m = 0; m < 2; ++m) {
#pragma unroll
        for (int j = 0; j < 4; ++j) {
            int row = pwr + m * 16 + ((lane >> 4) << 2) + j;
            float rd = 1.f / (rsum_lds[row][0] + rsum_lds[row][1]);
#pragma unroll
            for (int n = 0; n < 4; ++n) {
                float v = accp[m][n][j] * rd;
                v = v > 0.f ? v : (__expf(v) - 1.f);
                Op[(size_t)(row0 + row) * 512 + pwc + n * 16 + (lane & 15)] = v;
            }
        }
    }
}

// ---------------- GEMM: C = A (M,K) * B^T (N,K), row-major, 3-ring counted-vmcnt ----------------
enum { E_PROJ = 0, E_PROJT, E_EXP, E_EXPC, E_EXPT, E_EXPMT, E_PART };

template <int EPI, int BM>
__global__ __launch_bounds__(256) void gemm_nt(const u16* __restrict__ A, const u16* __restrict__ B,
                                               void* __restrict__ Cv, void* __restrict__ CvT,
                                               const float* __restrict__ bias, float* __restrict__ rs,
                                               int M, int N, int K, int lda, int ldb, int ldc, int ldcT,
                                               float scale, long sAz, long sBz, long sCz, long sCzT,
                                               long sBias, long sRs, int ZK, long sAz2, long sBz2) {
    constexpr bool HAS_BIAS = (EPI == E_PROJ || EPI == E_PROJT);
    constexpr bool DO_EXP = (EPI == E_EXP || EPI == E_EXPC || EPI == E_EXPT || EPI == E_EXPMT);
    constexpr bool DO_MASK = (EPI == E_EXPMT);
    constexpr int RSUM = (EPI == E_EXPC) ? 2 : (DO_EXP ? 1 : 0);
    constexpr bool STORE_N = (EPI != E_PROJT);
    constexpr bool STORE_T = (EPI == E_PROJT || EPI == E_EXPT || EPI == E_EXPMT);

    constexpr int MF = BM / 32;
    constexpr int ITERS = BM * 32 / (256 * 8);
    constexpr int LOADS = ITERS * 2;
    constexpr int SM_STAGE = 3 * BM * 64;
    constexpr int SM_REPACK = BM * BM;
    __shared__ __align__(16) u16 smem[SM_STAGE > SM_REPACK ? SM_STAGE : SM_REPACK];
    const int tid = threadIdx.x;
    const int lane = tid & 63;
    const int wid = tid >> 6;
    const int wr = (wid >> 1) * (BM / 2);
    const int wc = (wid & 1) * (BM / 2);
    const int row0 = blockIdx.x * BM;
    const int col0 = blockIdx.y * BM;
    const long zo = blockIdx.z;
    const long hz = zo / ZK;
    const long kz = zo - hz * ZK;
    const u16* Az = A + hz * sAz + kz * sAz2;
    const u16* Bz = B + hz * sBz + kz * sBz2;
    const float* biasz = bias ? bias + zo * sBias : nullptr;
    float* rsz = rs ? rs + zo * sRs : nullptr;
    f32x4 acc[MF][MF] = {};

    auto As = [&](int buf) { return smem + buf * (BM * 64); };
    auto Bs = [&](int buf) { return smem + buf * (BM * 64) + BM * 32; };

    auto stage = [&](int buf, int k0) {
#pragma unroll
        for (int i = 0; i < ITERS; ++i) {
            int c = tid + i * 256;
            int r = c >> 2;
            int lch = (c & 3) ^ ((r >> 1) & 3);
            const u16* sa = Az + (size_t)(row0 + r) * lda + k0 + lch * 8;
            const u16* sb = Bz + (size_t)(col0 + r) * ldb + k0 + lch * 8;
#ifdef HAS_GLL
            __builtin_amdgcn_global_load_lds(
                (const __attribute__((address_space(1))) void*)sa,
                (__attribute__((address_space(3))) void*)(&As(buf)[c * 8]), 16, 0, 0);
            __builtin_amdgcn_global_load_lds(
                (const __attribute__((address_space(1))) void*)sb,
                (__attribute__((address_space(3))) void*)(&Bs(buf)[c * 8]), 16, 0, 0);
#else
            *reinterpret_cast<uint4*>(&As(buf)[c * 8]) = *reinterpret_cast<const uint4*>(sa);
            *reinterpret_cast<uint4*>(&Bs(buf)[c * 8]) = *reinterpret_cast<const uint4*>(sb);
#endif
        }
    };

    stage(0, 0);
    stage(1, 32);
    wbar<LOADS>();

    const int nsteps = K >> 5;
    for (int t = 0; t < nsteps; ++t) {
        const int bufc = t % 3;
        const bool more2 = (t + 2 < nsteps);
        if (more2) stage((t + 2) % 3, (t + 2) << 5);
        bf16x8 af[MF], bv[MF];
#pragma unroll
        for (int m = 0; m < MF; ++m) {
            int rr = wr + m * 16 + (lane & 15);
            int p = (lane >> 4) ^ ((rr >> 1) & 3);
            af[m] = *reinterpret_cast<const bf16x8*>(&As(bufc)[rr * 32 + p * 8]);
        }
#pragma unroll
        for (int n = 0; n < MF; ++n) {
            int rr = wc + n * 16 + (lane & 15);
            int p = (lane >> 4) ^ ((rr >> 1) & 3);
            bv[n] = *reinterpret_cast<const bf16x8*>(&Bs(bufc)[rr * 32 + p * 8]);
        }
#pragma unroll
        for (int m = 0; m < MF; ++m)
#pragma unroll
            for (int n = 0; n < MF; ++n)
                acc[m][n] = __builtin_amdgcn_mfma_f32_16x16x32_bf16(af[m], bv[n], acc[m][n], 0, 0, 0);
        if (more2)                 wbar<LOADS>();
        else if (t + 1 < nsteps)   wbar<0>();
        else                       __syncthreads();
    }

    // ---- math pass ----
#pragma unroll
    for (int m = 0; m < MF; ++m) {
#pragma unroll
        for (int n = 0; n < MF; ++n) {
#pragma unroll
            for (int j = 0; j < 4; ++j) {
                float v = acc[m][n][j];
                if (HAS_BIAS) v += biasz[col0 + wc + n * 16 + (lane & 15)];
                if (DO_EXP) {
                    v = __expf(v * scale);
                    if (DO_MASK &&
                        row0 + wr + m * 16 + ((lane >> 4) << 2) + j ==
                        col0 + wc + n * 16 + (lane & 15)) v = 0.f;
                }
                acc[m][n][j] = v;
            }
        }
    }

    // ---- fused row/col sums (atomic partials) ----
    if (RSUM == 1) {
#pragma unroll
        for (int m = 0; m < MF; ++m) {
#pragma unroll
            for (int j = 0; j < 4; ++j) {
                float p = 0.f;
#pragma unroll
                for (int n = 0; n < MF; ++n) p += acc[m][n][j];
                p += __shfl_xor(p, 1); p += __shfl_xor(p, 2);
                p += __shfl_xor(p, 4); p += __shfl_xor(p, 8);
                if ((lane & 15) == 0)
                    atomicAdd(rsz + row0 + wr + m * 16 + ((lane >> 4) << 2) + j, p);
            }
        }
    } else if (RSUM == 2) {
#pragma unroll
        for (int n = 0; n < MF; ++n) {
            float p = 0.f;
#pragma unroll
            for (int m = 0; m < MF; ++m)
#pragma unroll
                for (int j = 0; j < 4; ++j) p += acc[m][n][j];
            p += __shfl_xor(p, 16); p += __shfl_xor(p, 32);
            if (lane < 16) atomicAdd(rsz + col0 + wc + n * 16 + lane, p);
        }
    }

    char* lc = reinterpret_cast<char*>(smem);
    if (STORE_N) {
#pragma unroll
        for (int m = 0; m < MF; ++m) {
#pragma unroll
            for (int n = 0; n < MF; ++n) {
#pragma unroll
                for (int j = 0; j < 4; ++j) {
                    int lrow = wr + m * 16 + ((lane >> 4) << 2) + j;
                    int lcol = wc + n * 16 + (lane & 15);
                    u32 byte = (u32)((lrow * BM + lcol) * 2) ^ (((lrow >> 2) & 3) << 5);
                    *reinterpret_cast<u16*>(lc + byte) = f2bf(acc[m][n][j]);
                }
            }
        }
        __syncthreads();
        constexpr int CH = BM / 8;
        constexpr int NIT = BM * CH / 256;
        u16* Cp = reinterpret_cast<u16*>(Cv) + zo * sCz;
#pragma unroll
        for (int it = 0; it < NIT; ++it) {
            int idx = it * 256 + tid;
            int rrow = idx / CH, c8 = idx % CH;
            u32 byte = (u32)((rrow * BM + c8 * 8) * 2) ^ (((rrow >> 2) & 3) << 5);
            u16x8 val = *reinterpret_cast<const u16x8*>(lc + byte);
            *reinterpret_cast<u16x8*>(Cp + (size_t)(row0 + rrow) * ldc + col0 + c8 * 8) = val;
        }
    }
    if (STORE_T) {
        __syncthreads();
#pragma unroll
        for (int m = 0; m < MF; ++m) {
#pragma unroll
            for (int n = 0; n < MF; ++n) {
                int lcol = wc + n * 16 + (lane & 15);
                int lrow0 = wr + m * 16 + ((lane >> 4) << 2);
                u32 byte = (u32)((lcol * BM + lrow0) * 2) ^ ((u32)(lcol & 7) << 4);
                u32 lo = (u32)f2bf(acc[m][n][0]) | ((u32)f2bf(acc[m][n][1]) << 16);
                u32 hi = (u32)f2bf(acc[m][n][2]) | ((u32)f2bf(acc[m][n][3]) << 16);
                uint2 pk; pk.x = lo; pk.y = hi;
                *reinterpret_cast<uint2*>(lc + byte) = pk;
            }
        }
        __syncthreads();
        constexpr int CHT = BM / 8;
        constexpr int NITT = BM * CHT / 256;
        u16* Tp = reinterpret_cast<u16*>(CvT) + zo * sCzT;
#pragma unroll
        for (int it = 0; it < NITT; ++it) {
            int idx = it * 256 + tid;
            int c = idx / CHT, r8 = idx % CHT;
            u32 byte = (u32)((c * BM + r8 * 8) * 2) ^ ((u32)(c & 7) << 4);
            u16x8 val = *reinterpret_cast<const u16x8*>(lc + byte);
            *reinterpret_cast<u16x8*>(Tp + (size_t)(col0 + c) * ldcT + row0 + r8 * 8) = val;
        }
    }
}

// ---------------- stage-2 reduce: out[row][d] = sum_h elu((1/rd_h[row]) * part[h][row][d]) ----------------
__global__ __launch_bounds__(256) void reduce_h_elu_kernel(const u16* __restrict__ part,
                                                           float* __restrict__ out, int R, int H,
                                                           const float* __restrict__ rd) {
    int i = blockIdx.x * 256 + threadIdx.x;
    int row = i >> 6, c8 = i & 63;
    long plane = (long)R * 512;
    const u16* p = part + (size_t)row * 512 + c8 * 8;
    float s[8] = {};
    for (int h = 0; h < H; ++h) {
        u16x8 x = *reinterpret_cast<const u16x8*>(p + (size_t)h * plane);
        float r = rd ? 1.f / rd[(size_t)h * R + row] : 1.f;
#pragma unroll
        for (int j = 0; j < 8; ++j) {
            float v = bf2f(x[j]) * r;
            s[j] += v > 0.f ? v : (__expf(v) - 1.f);
        }
    }
    float4* o = reinterpret_cast<float4*>(out + (size_t)row * 512 + c8 * 8);
    o[0] = float4{s[0], s[1], s[2], s[3]};
    o[1] = float4{s[4], s[5], s[6], s[7]};
}

// ---------------- combines (float4) ----------------
__global__ __launch_bounds__(256) void combine_obj_kernel(const float4* __restrict__ feat,
        const float4* __restrict__ a, const float4* __restrict__ b,
        const float4* __restrict__ c, const float4* __restrict__ d,
        float4* __restrict__ out, ushort4* __restrict__ outbf) {
    int i = blockIdx.x * 256 + threadIdx.x;
    int r = i >> 8, c4 = i & 255;
    size_t half = (size_t)r * 128 + (c4 & 127);
    float4 t1 = (c4 < 128) ? a[half] : b[half];
    float4 t2 = (c4 < 128) ? c[half] : d[half];
    float4 f = feat[i];
    float4 o;
    o.x = (f.x + t1.x + t2.x) * (1.f / 3.f);
    o.y = (f.y + t1.y + t2.y) * (1.f / 3.f);
    o.z = (f.z + t1.z + t2.z) * (1.f / 3.f);
    o.w = (f.w + t1.w + t2.w) * (1.f / 3.f);
    out[i] = o;
    ushort4 ob; ob.x = f2bf(o.x); ob.y = f2bf(o.y); ob.z = f2bf(o.z); ob.w = f2bf(o.w);
    outbf[i] = ob;
}

__global__ __launch_bounds__(256) void combine_rel1_kernel(const float4* __restrict__ feat,
        const float4* __restrict__ a, const float4* __restrict__ b, ushort4* __restrict__ outbf) {
    int i = blockIdx.x * 256 + threadIdx.x;
    int r = i >> 8, c4 = i & 255;
    size_t half = (size_t)r * 128 + (c4 & 127);
    float4 t = (c4 < 128) ? a[half] : b[half];
    float4 f = feat[i];
    ushort4 ob;
    ob.x = f2bf((f.x + t.x) * 0.5f); ob.y = f2bf((f.y + t.y) * 0.5f);
    ob.z = f2bf((f.z + t.z) * 0.5f); ob.w = f2bf((f.w + t.w) * 0.5f);
    outbf[i] = ob;
}

__global__ __launch_bounds__(256) void combine_rel2_kernel(const float4* __restrict__ feat,
        const float4* __restrict__ a, const float4* __restrict__ b, float4* __restrict__ out) {
    int i = blockIdx.x * 256 + threadIdx.x;
    int r = i >> 8, c4 = i & 255;
    size_t half = (size_t)r * 128 + (c4 & 127);
    float4 t = (c4 < 128) ? a[half] : b[half];
    float4 f = feat[i];
    float4 o;
    o.x = (f.x + t.x) * 0.5f; o.y = (f.y + t.y) * 0.5f;
    o.z = (f.z + t.z) * 0.5f; o.w = (f.w + t.w) * 0.5f;
    out[i] = o;
}

extern "C" void kernel_launch(void* const* d_in, const int* in_sizes, int n_in,
                              void* d_out, int out_size, void* d_ws, size_t ws_size,
                              hipStream_t stream) {
    (void)in_sizes; (void)n_in; (void)out_size; (void)ws_size;
    const float* feat_obj = (const float*)d_in[0];
    const float* feat_rel = (const float*)d_in[1];
    const float* W_cat = (const float*)d_in[2];
    const float* b_cat = (const float*)d_in[3];
    const float* W_out = (const float*)d_in[4];
    const float* b_out = (const float*)d_in[5];
    float* out_obj = (float*)d_out;
    float* out_rel = (float*)d_out + (size_t)2048 * 1024;

    char* w = (char*)d_ws;
    auto alloc = [&](size_t bytes) { void* p = (void*)w; w += (bytes + 255) & ~(size_t)255; return p; };
    u16* bf_obj  = (u16*)alloc((size_t)2048 * 1024 * 2);
    u16* bf_rel  = (u16*)alloc((size_t)4096 * 1024 * 2);
    u16* bf_obj2 = (u16*)alloc((size_t)2048 * 1024 * 2);
    u16* bf_rel2 = (u16*)alloc((size_t)4096 * 1024 * 2);
    u16* Wt_cat  = (u16*)alloc((size_t)12 * 512 * 1024 * 2);     // 12 MiB
    // stage-1 projections (all live simultaneously for the fused mega-dispatch)
    u16* Q01   = (u16*)alloc((size_t)2 * 2048 * 512 * 2);   // z0=m0.q, z1=m1.q
    u16* K02   = (u16*)alloc((size_t)2 * 2048 * 512 * 2);   // z0=m0.k, z1=m2.k
    u16* Q2    = (u16*)alloc((size_t)4096 * 512 * 2);
    u16* K1    = (u16*)alloc((size_t)4096 * 512 * 2);
    u16* Vq01T = (u16*)alloc((size_t)2 * 512 * 2048 * 2);   // z0=m0.qvT, z1=m1.qvT
    u16* Vk02T = (u16*)alloc((size_t)2 * 512 * 2048 * 2);   // z0=m0.kvT, z1=m2.kvT
    u16* Vk1T  = (u16*)alloc((size_t)512 * 4096 * 2);
    u16* Vq2T  = (u16*)alloc((size_t)512 * 4096 * 2);
    // stage-2 buffers
    u16* Pq2   = (u16*)alloc((size_t)2 * 2048 * 3072 * 2);  // z0=mha0.q, z1=mha1.k (obj2 input)
    u16* Pk2   = (u16*)alloc((size_t)2 * 4096 * 3072 * 2);  // z0=mha0.k, z1=mha1.q (rel2 input)
    u16* VTa   = (u16*)alloc((size_t)2 * 3072 * 2048 * 2);  // z0=mha0.qvT, z1=mha1.kvT
    u16* VTs   = (u16*)alloc((size_t)3072 * 2048 * 2);
    u16* Sbuf  = (u16*)alloc((size_t)6 * 4096 * 2048 * 2);  // 96 MiB
    // Wt2 ALIASES Sbuf: Wt2 written+read before the first Sbuf (score) write;
    // all stage-2 projection dispatches precede the score GEMMs on the stream.
    u16* Wt2   = Sbuf;                                      // 48 MiB of the 96
    u16* part  = (u16*)alloc((size_t)6 * 4096 * 512 * 2);
    float* rdAll = (float*)alloc((size_t)36864 * 4);
    float* rdQ = rdAll;               // 6*2048
    float* rdM = rdAll + 12288;       // 6*4096
    float* sub_obj  = (float*)alloc((size_t)2048 * 512 * 4);
    float* obj_sub  = (float*)alloc((size_t)2048 * 512 * 4);
    float* sub_rel  = (float*)alloc((size_t)2048 * 512 * 4);
    float* obj_rel  = (float*)alloc((size_t)2048 * 512 * 4);
    float* rel_obj  = (float*)alloc((size_t)4096 * 512 * 4);
    float* rel_sub  = (float*)alloc((size_t)4096 * 512 * 4);
    float* rel_obj2 = (float*)alloc((size_t)4096 * 512 * 4);
    float* rel_sub2 = (float*)alloc((size_t)4096 * 512 * 4);

    zero_kernel<<<144, 256, 0, stream>>>(rdAll, 36864);
    cvt_bf16_kernel<<<2048, 256, 0, stream>>>((const float4*)feat_obj, (ushort4*)bf_obj, 2048 * 1024 / 4);
    cvt_bf16_kernel<<<4096, 256, 0, stream>>>((const float4*)feat_rel, (ushort4*)bf_rel, 4096 * 1024 / 4);
    transcvt_kernel<<<dim3(16, 32, 12), dim3(32, 8), 0, stream>>>(W_cat, Wt_cat, 1024, 512);
    transcvt_kernel<<<dim3(96, 32, 8), dim3(32, 8), 0, stream>>>(W_out, Wt2, 1024, 3072);

    const float sc1 = 0.08838834764831845f;  // 1/sqrt(128)
    const float sc2 = 0.04419417382415922f;  // 1/sqrt(512)
    const long planeW = (long)512 * 1024;
    const long planeW2 = (long)3072 * 1024;
    const long NIL = 0;

    // ---------------- stage-1 projections (8 dispatches, z-batched by input+layout) ----------------
    // q: m0(plane0)+m1(plane4), input bf_obj
    gemm_nt<E_PROJ, 64><<<dim3(32, 8, 2), 256, 0, stream>>>(
        bf_obj, Wt_cat, Q01, nullptr, b_cat, nullptr,
        2048, 512, 1024, 1024, 1024, 512, 0, 0.f, NIL, 4 * planeW, (long)2048 * 512, NIL,
        4L * 512, NIL, 1, NIL, NIL);
    // k: m0(plane1)+m2(plane9), input bf_obj
    gemm_nt<E_PROJ, 64><<<dim3(32, 8, 2), 256, 0, stream>>>(
        bf_obj, Wt_cat + planeW, K02, nullptr, b_cat + 512, nullptr,
        2048, 512, 1024, 1024, 1024, 512, 0, 0.f, NIL, 8 * planeW, (long)2048 * 512, NIL,
        8L * 512, NIL, 1, NIL, NIL);
    // qvT: m0(plane2)+m1(plane6), input bf_obj
    gemm_nt<E_PROJT, 64><<<dim3(32, 8, 2), 256, 0, stream>>>(
        bf_obj, Wt_cat + 2 * planeW, nullptr, Vq01T, b_cat + 1024, nullptr,
        2048, 512, 1024, 1024, 1024, 0, 2048, 0.f, NIL, 4 * planeW, NIL, (long)512 * 2048,
        4L * 512, NIL, 1, NIL, NIL);
    // kvT: m0(plane3)+m2(plane11), input bf_obj
    gemm_nt<E_PROJT, 64><<<dim3(32, 8, 2), 256, 0, stream>>>(
        bf_obj, Wt_cat + 3 * planeW, nullptr, Vk02T, b_cat + 1536, nullptr,
        2048, 512, 1024, 1024, 1024, 0, 2048, 0.f, NIL, 8 * planeW, NIL, (long)512 * 2048,
        8L * 512, NIL, 1, NIL, NIL);
    // singles (input bf_rel): m1.k(plane5), m2.q(plane8), m1.kvT(plane7), m2.qvT(plane10)
    gemm_nt<E_PROJ, 64><<<dim3(64, 8, 1), 256, 0, stream>>>(
        bf_rel, Wt_cat + 5 * planeW, K1, nullptr, b_cat + 5 * 512, nullptr,
        4096, 512, 1024, 1024, 1024, 512, 0, 0.f, NIL, NIL, NIL, NIL, NIL, NIL, 1, NIL, NIL);
    gemm_nt<E_PROJ, 64><<<dim3(64, 8, 1), 256, 0, stream>>>(
        bf_rel, Wt_cat + 8 * planeW, Q2, nullptr, b_cat + 8 * 512, nullptr,
        4096, 512, 1024, 1024, 1024, 512, 0, 0.f, NIL, NIL, NIL, NIL, NIL, NIL, 1, NIL, NIL);
    gemm_nt<E_PROJT, 64><<<dim3(64, 8, 1), 256, 0, stream>>>(
        bf_rel, Wt_cat + 7 * planeW, nullptr, Vk1T, b_cat + 7 * 512, nullptr,
        4096, 512, 1024, 1024, 1024, 0, 4096, 0.f, NIL, NIL, NIL, NIL, NIL, NIL, 1, NIL, NIL);
    gemm_nt<E_PROJT, 64><<<dim3(64, 8, 1), 256, 0, stream>>>(
        bf_rel, Wt_cat + 10 * planeW, nullptr, Vq2T, b_cat + 10 * 512, nullptr,
        4096, 512, 1024, 1024, 1024, 0, 4096, 0.f, NIL, NIL, NIL, NIL, NIL, NIL, 1, NIL, NIL);

    // ---------------- fused stage-1 attention: 6 groups x 4 heads in one dispatch ----------------
    FCfg fc;
    fc.g[0] = { Q01,                    K02,                    Vk02T,                    sub_obj, 2048, 2048, 1 };
    fc.g[1] = { K02,                    Q01,                    Vq01T,                    obj_sub, 2048, 2048, 1 };
    fc.g[2] = { Q01 + (size_t)2048*512, K1,                     Vk1T,                     sub_rel, 2048, 4096, 0 };
    fc.g[3] = { K1,                     Q01 + (size_t)2048*512, Vq01T + (size_t)512*2048, rel_sub, 4096, 2048, 0 };
    fc.g[4] = { Q2,                     K02 + (size_t)2048*512, Vk02T + (size_t)512*2048, rel_obj, 4096, 2048, 0 };
    fc.g[5] = { K02 + (size_t)2048*512, Q2,                     Vq2T,                     obj_rel, 2048, 4096, 0 };
    fused_attn1_kernel<<<dim3(64, 1, 24), 256, 0, stream>>>(fc, sc1);

    combine_obj_kernel<<<2048, 256, 0, stream>>>((const float4*)feat_obj, (const float4*)sub_obj,
        (const float4*)obj_sub, (const float4*)sub_rel, (const float4*)obj_rel,
        (float4*)out_obj, (ushort4*)bf_obj2);
    combine_rel1_kernel<<<4096, 256, 0, stream>>>((const float4*)feat_rel, (const float4*)rel_obj,
        (const float4*)rel_sub, (ushort4*)bf_rel2);

    // ---------------- stage-2 projections (3 dispatches, z-batched; read Wt2 BEFORE Sbuf writes) ----------------
    // obj2 x planes {0 (mha0.q), 5 (mha1.k)} -> Pq2
    gemm_nt<E_PROJ, 128><<<dim3(16, 24, 2), 256, 0, stream>>>(
        bf_obj2, Wt2, Pq2, nullptr, b_out, nullptr,
        2048, 3072, 1024, 1024, 1024, 3072, 0, 0.f, NIL, 5 * planeW2, (long)2048 * 3072, NIL,
        5L * 3072, NIL, 1, NIL, NIL);
    // rel2 x planes {1 (mha0.k), 4 (mha1.q)} -> Pk2
    gemm_nt<E_PROJ, 128><<<dim3(32, 24, 2), 256, 0, stream>>>(
        bf_rel2, Wt2 + planeW2, Pk2, nullptr, b_out + 3072, nullptr,
        4096, 3072, 1024, 1024, 1024, 3072, 0, 0.f, NIL, 3 * planeW2, (long)4096 * 3072, NIL,
        3L * 3072, NIL, 1, NIL, NIL);
    // obj2 x planes {2 (mha0.qv), 7 (mha1.kv)} -> VTa (transposed)
    gemm_nt<E_PROJT, 128><<<dim3(16, 24, 2), 256, 0, stream>>>(
        bf_obj2, Wt2 + 2 * planeW2, nullptr, VTa, b_out + 2 * 3072, nullptr,
        2048, 3072, 1024, 1024, 1024, 0, 2048, 0.f, NIL, 5 * planeW2, NIL, (long)3072 * 2048,
        5L * 3072, NIL, 1, NIL, NIL);

    const long spl2 = (long)4096 * 2048;
    const long vpl2 = (long)4096 * 512;

    // ---------------- stage 2 mha0: a2 only (swapped scores) ----------------
    {
        gemm_nt<E_EXPC, 128><<<dim3(32, 16, 6), 256, 0, stream>>>(
            Pk2, Pq2, Sbuf, nullptr, nullptr, rdQ,
            4096, 2048, 512, 3072, 3072, 2048, 0, sc2, 512, 512, spl2, NIL, NIL, 2048, 1, NIL, NIL);
        scale_rows_kernel<<<3072 * 2048 / 2048, 256, 0, stream>>>(VTa, VTs, rdQ, 2048, 9);
        gemm_nt<E_PART, 128><<<dim3(32, 4, 6), 256, 0, stream>>>(
            Sbuf, VTs, part, nullptr, nullptr, nullptr,
            4096, 512, 2048, 2048, 2048, 512, 0, 0.f, spl2, 512L * 2048, vpl2, NIL, NIL, NIL,
            1, NIL, NIL);
        reduce_h_elu_kernel<<<1024, 256, 0, stream>>>(part, rel_sub2, 4096, 6, nullptr);
    }
    // ---------------- stage 2 mha1: a1 only ----------------
    {
        gemm_nt<E_EXP, 128><<<dim3(32, 16, 6), 256, 0, stream>>>(
            Pk2 + (size_t)4096 * 3072, Pq2 + (size_t)2048 * 3072, Sbuf, nullptr, nullptr, rdM,
            4096, 2048, 512, 3072, 3072, 2048, 0, sc2, 512, 512, spl2, NIL, NIL, 4096, 1, NIL, NIL);
        gemm_nt<E_PART, 128><<<dim3(32, 4, 6), 256, 0, stream>>>(
            Sbuf, VTa + (size_t)3072 * 2048, part, nullptr, nullptr, nullptr,
            4096, 512, 2048, 2048, 2048, 512, 0, 0.f, spl2, 512L * 2048, vpl2, NIL, NIL, NIL,
            1, NIL, NIL);
        reduce_h_elu_kernel<<<1024, 256, 0, stream>>>(part, rel_obj2, 4096, 6, rdM);
    }

    combine_rel2_kernel<<<4096, 256, 0, stream>>>((const float4*)feat_rel, (const float4*)rel_obj2,
        (const float4*)rel_sub2, (float4*)out_rel);
}

// Round 11
// 812.680 us; speedup vs baseline: 1.3056x; 1.0011x over previous
//
#include <hip/hip_runtime.h>

typedef unsigned short u16;
typedef unsigned int u32;
typedef __attribute__((ext_vector_type(4))) float f32x4;
typedef __attribute__((ext_vector_type(8))) __bf16 bf16x8;
typedef __attribute__((ext_vector_type(8))) unsigned short u16x8;

#if defined(__has_builtin)
#if __has_builtin(__builtin_amdgcn_global_load_lds)
#define HAS_GLL 1
#endif
#endif

__device__ __forceinline__ u16 f2bf(float f) {
    u32 u = __builtin_bit_cast(u32, f);
    u += 0x7fffu + ((u >> 16) & 1u);
    return (u16)(u >> 16);
}
__device__ __forceinline__ float bf2f(u16 x) {
    return __builtin_bit_cast(float, (u32)x << 16);
}

// counted-vmcnt barrier
template <int N> __device__ __forceinline__ void wbar() {
#ifdef HAS_GLL
    if constexpr (N == 0)
        asm volatile("s_waitcnt vmcnt(0)\n\ts_barrier" ::: "memory");
    else if constexpr (N == 2)
        asm volatile("s_waitcnt vmcnt(2)\n\ts_barrier" ::: "memory");
    else
        asm volatile("s_waitcnt vmcnt(4)\n\ts_barrier" ::: "memory");
#else
    __syncthreads();
#endif
}

// full drain barrier (vm + lgkm)
__device__ __forceinline__ void fbar() {
#ifdef HAS_GLL
    asm volatile("s_waitcnt vmcnt(0) lgkmcnt(0)\n\ts_barrier" ::: "memory");
#else
    __syncthreads();
#endif
}

// plain barrier (no drain) — used only where all readers' LDS ops have retired
__device__ __forceinline__ void rbar() {
#ifdef HAS_GLL
    asm volatile("s_barrier" ::: "memory");
#else
    __syncthreads();
#endif
}

// ---------------- utility kernels ----------------
__global__ __launch_bounds__(256) void zero_kernel(float* __restrict__ p, int n) {
    int i = blockIdx.x * 256 + threadIdx.x;
    if (i < n) p[i] = 0.f;
}

__global__ __launch_bounds__(256) void cvt_bf16_kernel(const float4* __restrict__ in,
                                                       ushort4* __restrict__ out, int n4) {
    int i = blockIdx.x * 256 + threadIdx.x;
    if (i < n4) {
        float4 v = in[i];
        ushort4 o;
        o.x = f2bf(v.x); o.y = f2bf(v.y); o.z = f2bf(v.z); o.w = f2bf(v.w);
        out[i] = o;
    }
}

// transpose + convert: W [B][K][N] f32 -> Wt [B][N][K] bf16
__global__ __launch_bounds__(256) void transcvt_kernel(const float* __restrict__ W,
                                                       u16* __restrict__ Wt, int K, int N) {
    __shared__ u16 t[32][33];
    int b = blockIdx.z;
    const float* Wb = W + (size_t)b * K * N;
    u16* Wtb = Wt + (size_t)b * K * N;
    int n0 = blockIdx.x * 32, k0 = blockIdx.y * 32;
    int tx = threadIdx.x, ty = threadIdx.y;
#pragma unroll
    for (int j = 0; j < 4; ++j)
        t[ty + j * 8][tx] = f2bf(Wb[(size_t)(k0 + ty + j * 8) * N + n0 + tx]);
    __syncthreads();
#pragma unroll
    for (int j = 0; j < 4; ++j)
        Wtb[(size_t)(n0 + ty + j * 8) * K + k0 + tx] = t[tx][ty + j * 8];
}

// ---------------- divide rows of [R][C] bf16 by sums[(r>>lg)*C + c] ----------------
__global__ __launch_bounds__(256) void scale_rows_kernel(const u16* __restrict__ in,
                                                         u16* __restrict__ out,
                                                         const float* __restrict__ rd,
                                                         int C, int lgdk) {
    int i = (blockIdx.x * 256 + threadIdx.x) * 8;
    int r = i / C, c = i % C;
    const float* rdp = rd + ((size_t)(r >> lgdk)) * C + c;
    u16x8 x = *reinterpret_cast<const u16x8*>(in + i);
    u16x8 o;
#pragma unroll
    for (int j = 0; j < 8; ++j) o[j] = f2bf(bf2f(x[j]) / rdp[j]);
    *reinterpret_cast<u16x8*>(out + i) = o;
}

// ---------------- fused stage-1 attention (two-pass: NORM=1 a1 + rsinv; NORM=0 a2 uses rsinv) ----------------
// NORM=1: out = elu( (expS @ V^T) / rowsum ), writes rsinv[h][row] = 1/rowsum.
// NORM=0: P = expS * rsinv[contraction idx]  (exact per-query softmax), out = elu(P @ V^T).
struct FGrp { const u16* A; const u16* B; const u16* V; float* O; float* rs; int M; int NK; int mask; };
struct FCfg { FGrp g[3]; };

template <int NORM>
__global__ __launch_bounds__(256) void fused_attn1_kernel(FCfg cfg, float scale) {
    __shared__ __align__(16) u16 Abuf[4 * 2048];       // 16KB [kb][64 rows][32 dk]
    __shared__ __align__(16) u16 Bbuf[2][4 * 2048];    // 32KB: double-buffered key tiles
    __shared__ __align__(16) u16 Vbuf[2 * 4096];       // 16KB [kb][128 d][32 keys]
    __shared__ __align__(16) u16 Pbuf[2 * 2048];       // 8KB  [kb][64 rows][32 keys]
    __shared__ float rsum_lds[64][2];
    const int gi = blockIdx.z >> 2, h = blockIdx.z & 3;
    FGrp G = (gi == 0) ? cfg.g[0] : (gi == 1) ? cfg.g[1] : cfg.g[2];
    const int row0 = blockIdx.x * 64;
    if (row0 >= G.M) return;
    const u16* Ap = G.A + h * 128;                     // lda 512
    const u16* Bp = G.B + h * 128;                     // ldb 512
    const u16* Vp = G.V + (size_t)h * 128 * G.NK;      // ldv NK
    float* Op = G.O + h * 128;                         // ldo 512
    const int ldv = G.NK;
    const int tid = threadIdx.x, lane = tid & 63, wid = tid >> 6;
    const int swr = (wid >> 1) * 32, swc = (wid & 1) * 32;
    const int pwr = swr, pwc = (wid & 1) * 64;

    auto gld = [&](const u16* src, u16* dst) {
#ifdef HAS_GLL
        __builtin_amdgcn_global_load_lds(
            (const __attribute__((address_space(1))) void*)src,
            (__attribute__((address_space(3))) void*)dst, 16, 0, 0);
#else
        *reinterpret_cast<uint4*>(dst) = *reinterpret_cast<const uint4*>(src);
#endif
    };
    auto stageB = [&](int t, int buf) {
#pragma unroll
        for (int it = 0; it < 4; ++it) {
            int c = tid + it * 256;
            int kb = c >> 8, cc = c & 255;
            int r = cc >> 2, lch = (cc & 3) ^ ((r >> 1) & 3);
            gld(Bp + (size_t)(t * 64 + r) * 512 + kb * 32 + lch * 8, &Bbuf[buf][kb * 2048 + cc * 8]);
        }
    };
    auto stageV = [&](int t) {
#pragma unroll
        for (int it = 0; it < 4; ++it) {
            int c = tid + it * 256;
            int kb = c >> 9, cc = c & 511;
            int r = cc >> 2, lch = (cc & 3) ^ ((r >> 1) & 3);
            gld(Vp + (size_t)r * ldv + t * 64 + kb * 32 + lch * 8, &Vbuf[kb * 4096 + cc * 8]);
        }
    };

    // prologue: A tile + B(0), B(1); drain; then issue V(0)
#pragma unroll
    for (int it = 0; it < 4; ++it) {
        int c = tid + it * 256;
        int kb = c >> 8, cc = c & 255;
        int r = cc >> 2, lch = (cc & 3) ^ ((r >> 1) & 3);
        gld(Ap + (size_t)(row0 + r) * 512 + kb * 32 + lch * 8, &Abuf[kb * 2048 + cc * 8]);
    }
    stageB(0, 0);
    stageB(1, 1);
    fbar();
    stageV(0);

    f32x4 accp[2][4] = {};
    float rsum[2][4] = {};
    const int nt = G.NK >> 6;
    for (int t = 0; t < nt; ++t) {
        const u16* Bc = &Bbuf[t & 1][0];
        // ---- S phase: 64 rows x 64 keys, dk = 128 (B(t) visible since last fbar) ----
        f32x4 accs[2][2] = {};
#pragma unroll
        for (int kk = 0; kk < 4; ++kk) {
            bf16x8 af[2], bf[2];
#pragma unroll
            for (int m = 0; m < 2; ++m) {
                int rr = swr + m * 16 + (lane & 15);
                int p = (lane >> 4) ^ ((rr >> 1) & 3);
                af[m] = *reinterpret_cast<const bf16x8*>(&Abuf[kk * 2048 + rr * 32 + p * 8]);
            }
#pragma unroll
            for (int n = 0; n < 2; ++n) {
                int rr = swc + n * 16 + (lane & 15);
                int p = (lane >> 4) ^ ((rr >> 1) & 3);
                bf[n] = *reinterpret_cast<const bf16x8*>(&Bc[kk * 2048 + rr * 32 + p * 8]);
            }
#pragma unroll
            for (int m = 0; m < 2; ++m)
#pragma unroll
                for (int n = 0; n < 2; ++n)
                    accs[m][n] = __builtin_amdgcn_mfma_f32_16x16x32_bf16(af[m], bf[n], accs[m][n], 0, 0, 0);
        }
        // ---- exp (+rsinv multiply | +rowsum) + P write (staging layout, chunk-XOR) ----
        float rsv[2];
        if (NORM == 0) {
#pragma unroll
            for (int n = 0; n < 2; ++n)
                rsv[n] = G.rs[(size_t)h * G.NK + t * 64 + swc + n * 16 + (lane & 15)];
        }
#pragma unroll
        for (int m = 0; m < 2; ++m) {
#pragma unroll
            for (int n = 0; n < 2; ++n) {
#pragma unroll
                for (int j = 0; j < 4; ++j) {
                    int prow = swr + m * 16 + ((lane >> 4) << 2) + j;
                    int pkey = swc + n * 16 + (lane & 15);
                    float v = __expf(accs[m][n][j] * scale);
                    if (NORM == 0) v *= rsv[n];
                    if (G.mask && (row0 + prow == t * 64 + pkey)) v = 0.f;
                    if (NORM == 1) rsum[m][j] += v;
                    Pbuf[(pkey >> 5) * 2048 + prow * 32 +
                         ((((pkey >> 3) & 3) ^ ((prow >> 1) & 3)) << 3) + (pkey & 7)] = f2bf(v);
                }
            }
        }
        fbar();                               // V(t) landed (all waves), P visible
        if (t + 2 < nt) stageB(t + 2, t & 1); // safe: S(t) readers done; drains at next fbar
        // ---- PV phase: out 64 rows x 128 d, contraction 64 keys ----
#pragma unroll
        for (int kk = 0; kk < 2; ++kk) {
            bf16x8 pf[2], vf[4];
#pragma unroll
            for (int m = 0; m < 2; ++m) {
                int rr = pwr + m * 16 + (lane & 15);
                int p = (lane >> 4) ^ ((rr >> 1) & 3);
                pf[m] = *reinterpret_cast<const bf16x8*>(&Pbuf[kk * 2048 + rr * 32 + p * 8]);
            }
#pragma unroll
            for (int n = 0; n < 4; ++n) {
                int dd = pwc + n * 16 + (lane & 15);
                int p = (lane >> 4) ^ ((dd >> 1) & 3);
                vf[n] = *reinterpret_cast<const bf16x8*>(&Vbuf[kk * 4096 + dd * 32 + p * 8]);
            }
#pragma unroll
            for (int m = 0; m < 2; ++m)
#pragma unroll
                for (int n = 0; n < 4; ++n)
                    accp[m][n] = __builtin_amdgcn_mfma_f32_16x16x32_bf16(pf[m], vf[n], accp[m][n], 0, 0, 0);
        }
        rbar();                               // all PV reads retired -> Vbuf/Pbuf reusable
        if (t + 1 < nt) stageV(t + 1);
    }

    if (NORM == 1) {
        // ---- rowsum merge across the 2 key-slice waves ----
#pragma unroll
        for (int m = 0; m < 2; ++m)
#pragma unroll
            for (int j = 0; j < 4; ++j) {
                float s = rsum[m][j];
                s += __shfl_xor(s, 1); s += __shfl_xor(s, 2);
                s += __shfl_xor(s, 4); s += __shfl_xor(s, 8);
                rsum[m][j] = s;
            }
        if ((lane & 15) == 0) {
#pragma unroll
            for (int m = 0; m < 2; ++m)
#pragma unroll
                for (int j = 0; j < 4; ++j)
                    rsum_lds[swr + m * 16 + ((lane >> 4) << 2) + j][wid & 1] = rsum[m][j];
        }
        __syncthreads();
        if (tid < 64)
            G.rs[(size_t)h * G.M + row0 + tid] = 1.f / (rsum_lds[tid][0] + rsum_lds[tid][1]);
        // ---- scale + ELU + store ----
#pragma unroll
        for (int m = 0; m < 2; ++m) {
#pragma unroll
            for (int j = 0; j < 4; ++j) {
                int row = pwr + m * 16 + ((lane >> 4) << 2) + j;
                float rd = 1.f / (rsum_lds[row][0] + rsum_lds[row][1]);
#pragma unroll
                for (int n = 0; n < 4; ++n) {
                    float v = accp[m][n][j] * rd;
                    v = v > 0.f ? v : (__expf(v) - 1.f);
                    Op[(size_t)(row0 + row) * 512 + pwc + n * 16 + (lane & 15)] = v;
                }
            }
        }
    } else {
        // ---- already normalized: ELU + store ----
#pragma unroll
        for (int m = 0; m < 2; ++m) {
#pragma unroll
            for (int j = 0; j < 4; ++j) {
                int row = pwr + m * 16 + ((lane >> 4) << 2) + j;
#pragma unroll
                for (int n = 0; n < 4; ++n) {
                    float v = accp[m][n][j];
                    v = v > 0.f ? v : (__expf(v) - 1.f);
                    Op[(size_t)(row0 + row) * 512 + pwc + n * 16 + (lane & 15)] = v;
                }
            }
        }
    }
}

// ---------------- GEMM: C = A (M,K) * B^T (N,K), row-major, 3-ring counted-vmcnt ----------------
enum { E_PROJ = 0, E_PROJT, E_EXP, E_EXPC, E_EXPT, E_EXPMT, E_PART };

template <int EPI, int BM>
__global__ __launch_bounds__(256) void gemm_nt(const u16* __restrict__ A, const u16* __restrict__ B,
                                               void* __restrict__ Cv, void* __restrict__ CvT,
                                               const float* __restrict__ bias, float* __restrict__ rs,
                                               int M, int N, int K, int lda, int ldb, int ldc, int ldcT,
                                               float scale, long sAz, long sBz, long sCz, long sCzT,
                                               long sBias, long sRs, int ZK, long sAz2, long sBz2) {
    constexpr bool HAS_BIAS = (EPI == E_PROJ || EPI == E_PROJT);
    constexpr bool DO_EXP = (EPI == E_EXP || EPI == E_EXPC || EPI == E_EXPT || EPI == E_EXPMT);
    constexpr bool DO_MASK = (EPI == E_EXPMT);
    constexpr int RSUM = (EPI == E_EXPC) ? 2 : (DO_EXP ? 1 : 0);
    constexpr bool STORE_N = (EPI != E_PROJT);
    constexpr bool STORE_T = (EPI == E_PROJT || EPI == E_EXPT || EPI == E_EXPMT);

    constexpr int MF = BM / 32;
    constexpr int ITERS = BM * 32 / (256 * 8);
    constexpr int LOADS = ITERS * 2;
    constexpr int SM_STAGE = 3 * BM * 64;
    constexpr int SM_REPACK = BM * BM;
    __shared__ __align__(16) u16 smem[SM_STAGE > SM_REPACK ? SM_STAGE : SM_REPACK];
    const int tid = threadIdx.x;
    const int lane = tid & 63;
    const int wid = tid >> 6;
    const int wr = (wid >> 1) * (BM / 2);
    const int wc = (wid & 1) * (BM / 2);
    const int row0 = blockIdx.x * BM;
    const int col0 = blockIdx.y * BM;
    const long zo = blockIdx.z;
    const long hz = zo / ZK;
    const long kz = zo - hz * ZK;
    const u16* Az = A + hz * sAz + kz * sAz2;
    const u16* Bz = B + hz * sBz + kz * sBz2;
    const float* biasz = bias ? bias + zo * sBias : nullptr;
    float* rsz = rs ? rs + zo * sRs : nullptr;
    f32x4 acc[MF][MF] = {};

    auto As = [&](int buf) { return smem + buf * (BM * 64); };
    auto Bs = [&](int buf) { return smem + buf * (BM * 64) + BM * 32; };

    auto stage = [&](int buf, int k0) {
#pragma unroll
        for (int i = 0; i < ITERS; ++i) {
            int c = tid + i * 256;
            int r = c >> 2;
            int lch = (c & 3) ^ ((r >> 1) & 3);
            const u16* sa = Az + (size_t)(row0 + r) * lda + k0 + lch * 8;
            const u16* sb = Bz + (size_t)(col0 + r) * ldb + k0 + lch * 8;
#ifdef HAS_GLL
            __builtin_amdgcn_global_load_lds(
                (const __attribute__((address_space(1))) void*)sa,
                (__attribute__((address_space(3))) void*)(&As(buf)[c * 8]), 16, 0, 0);
            __builtin_amdgcn_global_load_lds(
                (const __attribute__((address_space(1))) void*)sb,
                (__attribute__((address_space(3))) void*)(&Bs(buf)[c * 8]), 16, 0, 0);
#else
            *reinterpret_cast<uint4*>(&As(buf)[c * 8]) = *reinterpret_cast<const uint4*>(sa);
            *reinterpret_cast<uint4*>(&Bs(buf)[c * 8]) = *reinterpret_cast<const uint4*>(sb);
#endif
        }
    };

    stage(0, 0);
    stage(1, 32);
    wbar<LOADS>();

    const int nsteps = K >> 5;
    for (int t = 0; t < nsteps; ++t) {
        const int bufc = t % 3;
        const bool more2 = (t + 2 < nsteps);
        if (more2) stage((t + 2) % 3, (t + 2) << 5);
        bf16x8 af[MF], bv[MF];
#pragma unroll
        for (int m = 0; m < MF; ++m) {
            int rr = wr + m * 16 + (lane & 15);
            int p = (lane >> 4) ^ ((rr >> 1) & 3);
            af[m] = *reinterpret_cast<const bf16x8*>(&As(bufc)[rr * 32 + p * 8]);
        }
#pragma unroll
        for (int n = 0; n < MF; ++n) {
            int rr = wc + n * 16 + (lane & 15);
            int p = (lane >> 4) ^ ((rr >> 1) & 3);
            bv[n] = *reinterpret_cast<const bf16x8*>(&Bs(bufc)[rr * 32 + p * 8]);
        }
#pragma unroll
        for (int m = 0; m < MF; ++m)
#pragma unroll
            for (int n = 0; n < MF; ++n)
                acc[m][n] = __builtin_amdgcn_mfma_f32_16x16x32_bf16(af[m], bv[n], acc[m][n], 0, 0, 0);
        if (more2)                 wbar<LOADS>();
        else if (t + 1 < nsteps)   wbar<0>();
        else                       __syncthreads();
    }

    // ---- math pass ----
#pragma unroll
    for (int m = 0; m < MF; ++m) {
#pragma unroll
        for (int n = 0; n < MF; ++n) {
#pragma unroll
            for (int j = 0; j < 4; ++j) {
                float v = acc[m][n][j];
                if (HAS_BIAS) v += biasz[col0 + wc + n * 16 + (lane & 15)];
                if (DO_EXP) {
                    v = __expf(v * scale);
                    if (DO_MASK &&
                        row0 + wr + m * 16 + ((lane >> 4) << 2) + j ==
                        col0 + wc + n * 16 + (lane & 15)) v = 0.f;
                }
                acc[m][n][j] = v;
            }
        }
    }

    // ---- fused row/col sums (atomic partials) ----
    if (RSUM == 1) {
#pragma unroll
        for (int m = 0; m < MF; ++m) {
#pragma unroll
            for (int j = 0; j < 4; ++j) {
                float p = 0.f;
#pragma unroll
                for (int n = 0; n < MF; ++n) p += acc[m][n][j];
                p += __shfl_xor(p, 1); p += __shfl_xor(p, 2);
                p += __shfl_xor(p, 4); p += __shfl_xor(p, 8);
                if ((lane & 15) == 0)
                    atomicAdd(rsz + row0 + wr + m * 16 + ((lane >> 4) << 2) + j, p);
            }
        }
    } else if (RSUM == 2) {
#pragma unroll
        for (int n = 0; n < MF; ++n) {
            float p = 0.f;
#pragma unroll
            for (int m = 0; m < MF; ++m)
#pragma unroll
                for (int j = 0; j < 4; ++j) p += acc[m][n][j];
            p += __shfl_xor(p, 16); p += __shfl_xor(p, 32);
            if (lane < 16) atomicAdd(rsz + col0 + wc + n * 16 + lane, p);
        }
    }

    char* lc = reinterpret_cast<char*>(smem);
    if (STORE_N) {
#pragma unroll
        for (int m = 0; m < MF; ++m) {
#pragma unroll
            for (int n = 0; n < MF; ++n) {
#pragma unroll
                for (int j = 0; j < 4; ++j) {
                    int lrow = wr + m * 16 + ((lane >> 4) << 2) + j;
                    int lcol = wc + n * 16 + (lane & 15);
                    u32 byte = (u32)((lrow * BM + lcol) * 2) ^ (((lrow >> 2) & 3) << 5);
                    *reinterpret_cast<u16*>(lc + byte) = f2bf(acc[m][n][j]);
                }
            }
        }
        __syncthreads();
        constexpr int CH = BM / 8;
        constexpr int NIT = BM * CH / 256;
        u16* Cp = reinterpret_cast<u16*>(Cv) + zo * sCz;
#pragma unroll
        for (int it = 0; it < NIT; ++it) {
            int idx = it * 256 + tid;
            int rrow = idx / CH, c8 = idx % CH;
            u32 byte = (u32)((rrow * BM + c8 * 8) * 2) ^ (((rrow >> 2) & 3) << 5);
            u16x8 val = *reinterpret_cast<const u16x8*>(lc + byte);
            *reinterpret_cast<u16x8*>(Cp + (size_t)(row0 + rrow) * ldc + col0 + c8 * 8) = val;
        }
    }
    if (STORE_T) {
        __syncthreads();
#pragma unroll
        for (int m = 0; m < MF; ++m) {
#pragma unroll
            for (int n = 0; n < MF; ++n) {
                int lcol = wc + n * 16 + (lane & 15);
                int lrow0 = wr + m * 16 + ((lane >> 4) << 2);
                u32 byte = (u32)((lcol * BM + lrow0) * 2) ^ ((u32)(lcol & 7) << 4);
                u32 lo = (u32)f2bf(acc[m][n][0]) | ((u32)f2bf(acc[m][n][1]) << 16);
                u32 hi = (u32)f2bf(acc[m][n][2]) | ((u32)f2bf(acc[m][n][3]) << 16);
                uint2 pk; pk.x = lo; pk.y = hi;
                *reinterpret_cast<uint2*>(lc + byte) = pk;
            }
        }
        __syncthreads();
        constexpr int CHT = BM / 8;
        constexpr int NITT = BM * CHT / 256;
        u16* Tp = reinterpret_cast<u16*>(CvT) + zo * sCzT;
#pragma unroll
        for (int it = 0; it < NITT; ++it) {
            int idx = it * 256 + tid;
            int c = idx / CHT, r8 = idx % CHT;
            u32 byte = (u32)((c * BM + r8 * 8) * 2) ^ ((u32)(c & 7) << 4);
            u16x8 val = *reinterpret_cast<const u16x8*>(lc + byte);
            *reinterpret_cast<u16x8*>(Tp + (size_t)(col0 + c) * ldcT + row0 + r8 * 8) = val;
        }
    }
}

// ---------------- stage-2 reduce: out[row][d] = sum_h elu((1/rd_h[row]) * part[h][row][d]) ----------------
__global__ __launch_bounds__(256) void reduce_h_elu_kernel(const u16* __restrict__ part,
                                                           float* __restrict__ out, int R, int H,
                                                           const float* __restrict__ rd) {
    int i = blockIdx.x * 256 + threadIdx.x;
    int row = i >> 6, c8 = i & 63;
    long plane = (long)R * 512;
    const u16* p = part + (size_t)row * 512 + c8 * 8;
    float s[8] = {};
    for (int h = 0; h < H; ++h) {
        u16x8 x = *reinterpret_cast<const u16x8*>(p + (size_t)h * plane);
        float r = rd ? 1.f / rd[(size_t)h * R + row] : 1.f;
#pragma unroll
        for (int j = 0; j < 8; ++j) {
            float v = bf2f(x[j]) * r;
            s[j] += v > 0.f ? v : (__expf(v) - 1.f);
        }
    }
    float4* o = reinterpret_cast<float4*>(out + (size_t)row * 512 + c8 * 8);
    o[0] = float4{s[0], s[1], s[2], s[3]};
    o[1] = float4{s[4], s[5], s[6], s[7]};
}

// ---------------- combines (float4) ----------------
__global__ __launch_bounds__(256) void combine_obj_kernel(const float4* __restrict__ feat,
        const float4* __restrict__ a, const float4* __restrict__ b,
        const float4* __restrict__ c, const float4* __restrict__ d,
        float4* __restrict__ out, ushort4* __restrict__ outbf) {
    int i = blockIdx.x * 256 + threadIdx.x;
    int r = i >> 8, c4 = i & 255;
    size_t half = (size_t)r * 128 + (c4 & 127);
    float4 t1 = (c4 < 128) ? a[half] : b[half];
    float4 t2 = (c4 < 128) ? c[half] : d[half];
    float4 f = feat[i];
    float4 o;
    o.x = (f.x + t1.x + t2.x) * (1.f / 3.f);
    o.y = (f.y + t1.y + t2.y) * (1.f / 3.f);
    o.z = (f.z + t1.z + t2.z) * (1.f / 3.f);
    o.w = (f.w + t1.w + t2.w) * (1.f / 3.f);
    out[i] = o;
    ushort4 ob; ob.x = f2bf(o.x); ob.y = f2bf(o.y); ob.z = f2bf(o.z); ob.w = f2bf(o.w);
    outbf[i] = ob;
}

__global__ __launch_bounds__(256) void combine_rel1_kernel(const float4* __restrict__ feat,
        const float4* __restrict__ a, const float4* __restrict__ b, ushort4* __restrict__ outbf) {
    int i = blockIdx.x * 256 + threadIdx.x;
    int r = i >> 8, c4 = i & 255;
    size_t half = (size_t)r * 128 + (c4 & 127);
    float4 t = (c4 < 128) ? a[half] : b[half];
    float4 f = feat[i];
    ushort4 ob;
    ob.x = f2bf((f.x + t.x) * 0.5f); ob.y = f2bf((f.y + t.y) * 0.5f);
    ob.z = f2bf((f.z + t.z) * 0.5f); ob.w = f2bf((f.w + t.w) * 0.5f);
    outbf[i] = ob;
}

__global__ __launch_bounds__(256) void combine_rel2_kernel(const float4* __restrict__ feat,
        const float4* __restrict__ a, const float4* __restrict__ b, float4* __restrict__ out) {
    int i = blockIdx.x * 256 + threadIdx.x;
    int r = i >> 8, c4 = i & 255;
    size_t half = (size_t)r * 128 + (c4 & 127);
    float4 t = (c4 < 128) ? a[half] : b[half];
    float4 f = feat[i];
    float4 o;
    o.x = (f.x + t.x) * 0.5f; o.y = (f.y + t.y) * 0.5f;
    o.z = (f.z + t.z) * 0.5f; o.w = (f.w + t.w) * 0.5f;
    out[i] = o;
}

extern "C" void kernel_launch(void* const* d_in, const int* in_sizes, int n_in,
                              void* d_out, int out_size, void* d_ws, size_t ws_size,
                              hipStream_t stream) {
    (void)in_sizes; (void)n_in; (void)out_size; (void)ws_size;
    const float* feat_obj = (const float*)d_in[0];
    const float* feat_rel = (const float*)d_in[1];
    const float* W_cat = (const float*)d_in[2];
    const float* b_cat = (const float*)d_in[3];
    const float* W_out = (const float*)d_in[4];
    const float* b_out = (const float*)d_in[5];
    float* out_obj = (float*)d_out;
    float* out_rel = (float*)d_out + (size_t)2048 * 1024;

    char* w = (char*)d_ws;
    auto alloc = [&](size_t bytes) { void* p = (void*)w; w += (bytes + 255) & ~(size_t)255; return p; };
    u16* bf_obj  = (u16*)alloc((size_t)2048 * 1024 * 2);
    u16* bf_rel  = (u16*)alloc((size_t)4096 * 1024 * 2);
    u16* bf_obj2 = (u16*)alloc((size_t)2048 * 1024 * 2);
    u16* bf_rel2 = (u16*)alloc((size_t)4096 * 1024 * 2);
    u16* Wt_cat  = (u16*)alloc((size_t)12 * 512 * 1024 * 2);     // 12 MiB
    // stage-1 projections
    u16* Q01   = (u16*)alloc((size_t)2 * 2048 * 512 * 2);   // z0=m0.q, z1=m1.q
    u16* K02   = (u16*)alloc((size_t)2 * 2048 * 512 * 2);   // z0=m0.k, z1=m2.k
    u16* Q2    = (u16*)alloc((size_t)4096 * 512 * 2);
    u16* K1    = (u16*)alloc((size_t)4096 * 512 * 2);
    u16* Vq01T = (u16*)alloc((size_t)2 * 512 * 2048 * 2);   // z0=m0.qvT, z1=m1.qvT
    u16* Vk02T = (u16*)alloc((size_t)2 * 512 * 2048 * 2);   // z0=m0.kvT, z1=m2.kvT
    u16* Vk1T  = (u16*)alloc((size_t)512 * 4096 * 2);
    u16* Vq2T  = (u16*)alloc((size_t)512 * 4096 * 2);
    // stage-2 buffers
    u16* Pq2   = (u16*)alloc((size_t)2 * 2048 * 3072 * 2);  // z0=mha0.q, z1=mha1.k (obj2 input)
    u16* Pk2   = (u16*)alloc((size_t)2 * 4096 * 3072 * 2);  // z0=mha0.k, z1=mha1.q (rel2 input)
    u16* VTa   = (u16*)alloc((size_t)2 * 3072 * 2048 * 2);  // z0=mha0.qvT, z1=mha1.kvT
    u16* VTs   = (u16*)alloc((size_t)3072 * 2048 * 2);
    u16* Sbuf  = (u16*)alloc((size_t)6 * 4096 * 2048 * 2);  // 96 MiB
    // Wt2 ALIASES Sbuf: written+read before the first Sbuf (score) write.
    u16* Wt2   = Sbuf;                                      // 48 MiB of the 96
    u16* part  = (u16*)alloc((size_t)6 * 4096 * 512 * 2);
    float* rdAll = (float*)alloc((size_t)36864 * 4);
    float* rdQ = rdAll;               // 6*2048
    float* rdM = rdAll + 12288;       // 6*4096
    // stage-1 rsinv (written by fused pass 1, read by pass 2)
    float* rs0 = (float*)alloc((size_t)4 * 2048 * 4);
    float* rs1 = (float*)alloc((size_t)4 * 2048 * 4);
    float* rs2 = (float*)alloc((size_t)4 * 4096 * 4);
    float* sub_obj  = (float*)alloc((size_t)2048 * 512 * 4);
    float* obj_sub  = (float*)alloc((size_t)2048 * 512 * 4);
    float* sub_rel  = (float*)alloc((size_t)2048 * 512 * 4);
    float* obj_rel  = (float*)alloc((size_t)2048 * 512 * 4);
    float* rel_obj  = (float*)alloc((size_t)4096 * 512 * 4);
    float* rel_sub  = (float*)alloc((size_t)4096 * 512 * 4);
    float* rel_obj2 = (float*)alloc((size_t)4096 * 512 * 4);
    float* rel_sub2 = (float*)alloc((size_t)4096 * 512 * 4);

    zero_kernel<<<144, 256, 0, stream>>>(rdAll, 36864);
    cvt_bf16_kernel<<<2048, 256, 0, stream>>>((const float4*)feat_obj, (ushort4*)bf_obj, 2048 * 1024 / 4);
    cvt_bf16_kernel<<<4096, 256, 0, stream>>>((const float4*)feat_rel, (ushort4*)bf_rel, 4096 * 1024 / 4);
    transcvt_kernel<<<dim3(16, 32, 12), dim3(32, 8), 0, stream>>>(W_cat, Wt_cat, 1024, 512);
    transcvt_kernel<<<dim3(96, 32, 8), dim3(32, 8), 0, stream>>>(W_out, Wt2, 1024, 3072);

    const float sc1 = 0.08838834764831845f;  // 1/sqrt(128)
    const float sc2 = 0.04419417382415922f;  // 1/sqrt(512)
    const long planeW = (long)512 * 1024;
    const long planeW2 = (long)3072 * 1024;
    const long NIL = 0;

    // ---------------- stage-1 projections (8 dispatches, z-batched by input+layout) ----------------
    gemm_nt<E_PROJ, 64><<<dim3(32, 8, 2), 256, 0, stream>>>(
        bf_obj, Wt_cat, Q01, nullptr, b_cat, nullptr,
        2048, 512, 1024, 1024, 1024, 512, 0, 0.f, NIL, 4 * planeW, (long)2048 * 512, NIL,
        4L * 512, NIL, 1, NIL, NIL);
    gemm_nt<E_PROJ, 64><<<dim3(32, 8, 2), 256, 0, stream>>>(
        bf_obj, Wt_cat + planeW, K02, nullptr, b_cat + 512, nullptr,
        2048, 512, 1024, 1024, 1024, 512, 0, 0.f, NIL, 8 * planeW, (long)2048 * 512, NIL,
        8L * 512, NIL, 1, NIL, NIL);
    gemm_nt<E_PROJT, 64><<<dim3(32, 8, 2), 256, 0, stream>>>(
        bf_obj, Wt_cat + 2 * planeW, nullptr, Vq01T, b_cat + 1024, nullptr,
        2048, 512, 1024, 1024, 1024, 0, 2048, 0.f, NIL, 4 * planeW, NIL, (long)512 * 2048,
        4L * 512, NIL, 1, NIL, NIL);
    gemm_nt<E_PROJT, 64><<<dim3(32, 8, 2), 256, 0, stream>>>(
        bf_obj, Wt_cat + 3 * planeW, nullptr, Vk02T, b_cat + 1536, nullptr,
        2048, 512, 1024, 1024, 1024, 0, 2048, 0.f, NIL, 8 * planeW, NIL, (long)512 * 2048,
        8L * 512, NIL, 1, NIL, NIL);
    gemm_nt<E_PROJ, 64><<<dim3(64, 8, 1), 256, 0, stream>>>(
        bf_rel, Wt_cat + 5 * planeW, K1, nullptr, b_cat + 5 * 512, nullptr,
        4096, 512, 1024, 1024, 1024, 512, 0, 0.f, NIL, NIL, NIL, NIL, NIL, NIL, 1, NIL, NIL);
    gemm_nt<E_PROJ, 64><<<dim3(64, 8, 1), 256, 0, stream>>>(
        bf_rel, Wt_cat + 8 * planeW, Q2, nullptr, b_cat + 8 * 512, nullptr,
        4096, 512, 1024, 1024, 1024, 512, 0, 0.f, NIL, NIL, NIL, NIL, NIL, NIL, 1, NIL, NIL);
    gemm_nt<E_PROJT, 64><<<dim3(64, 8, 1), 256, 0, stream>>>(
        bf_rel, Wt_cat + 7 * planeW, nullptr, Vk1T, b_cat + 7 * 512, nullptr,
        4096, 512, 1024, 1024, 1024, 0, 4096, 0.f, NIL, NIL, NIL, NIL, NIL, NIL, 1, NIL, NIL);
    gemm_nt<E_PROJT, 64><<<dim3(64, 8, 1), 256, 0, stream>>>(
        bf_rel, Wt_cat + 10 * planeW, nullptr, Vq2T, b_cat + 10 * 512, nullptr,
        4096, 512, 1024, 1024, 1024, 0, 4096, 0.f, NIL, NIL, NIL, NIL, NIL, NIL, 1, NIL, NIL);

    // ---------------- fused stage-1 attention: pass 1 (a1 + rsinv), pass 2 (a2 via rsinv) ----------------
    FCfg f1, f2;
    f1.g[0] = { Q01,                    K02,                    Vk02T,                    sub_obj, rs0, 2048, 2048, 1 };
    f1.g[1] = { Q01 + (size_t)2048*512, K1,                     Vk1T,                     sub_rel, rs1, 2048, 4096, 0 };
    f1.g[2] = { Q2,                     K02 + (size_t)2048*512, Vk02T + (size_t)512*2048, rel_obj, rs2, 4096, 2048, 0 };
    fused_attn1_kernel<1><<<dim3(64, 1, 12), 256, 0, stream>>>(f1, sc1);
    f2.g[0] = { K02,                    Q01,                    Vq01T,                    obj_sub, rs0, 2048, 2048, 1 };
    f2.g[1] = { K1,                     Q01 + (size_t)2048*512, Vq01T + (size_t)512*2048, rel_sub, rs1, 4096, 2048, 0 };
    f2.g[2] = { K02 + (size_t)2048*512, Q2,                     Vq2T,                     obj_rel, rs2, 2048, 4096, 0 };
    fused_attn1_kernel<0><<<dim3(64, 1, 12), 256, 0, stream>>>(f2, sc1);

    combine_obj_kernel<<<2048, 256, 0, stream>>>((const float4*)feat_obj, (const float4*)sub_obj,
        (const float4*)obj_sub, (const float4*)sub_rel, (const float4*)obj_rel,
        (float4*)out_obj, (ushort4*)bf_obj2);
    combine_rel1_kernel<<<4096, 256, 0, stream>>>((const float4*)feat_rel, (const float4*)rel_obj,
        (const float4*)rel_sub, (ushort4*)bf_rel2);

    // ---------------- stage-2 projections (3 dispatches; read Wt2 BEFORE Sbuf writes) ----------------
    gemm_nt<E_PROJ, 128><<<dim3(16, 24, 2), 256, 0, stream>>>(
        bf_obj2, Wt2, Pq2, nullptr, b_out, nullptr,
        2048, 3072, 1024, 1024, 1024, 3072, 0, 0.f, NIL, 5 * planeW2, (long)2048 * 3072, NIL,
        5L * 3072, NIL, 1, NIL, NIL);
    gemm_nt<E_PROJ, 128><<<dim3(32, 24, 2), 256, 0, stream>>>(
        bf_rel2, Wt2 + planeW2, Pk2, nullptr, b_out + 3072, nullptr,
        4096, 3072, 1024, 1024, 1024, 3072, 0, 0.f, NIL, 3 * planeW2, (long)4096 * 3072, NIL,
        3L * 3072, NIL, 1, NIL, NIL);
    gemm_nt<E_PROJT, 128><<<dim3(16, 24, 2), 256, 0, stream>>>(
        bf_obj2, Wt2 + 2 * planeW2, nullptr, VTa, b_out + 2 * 3072, nullptr,
        2048, 3072, 1024, 1024, 1024, 0, 2048, 0.f, NIL, 5 * planeW2, NIL, (long)3072 * 2048,
        5L * 3072, NIL, 1, NIL, NIL);

    const long spl2 = (long)4096 * 2048;
    const long vpl2 = (long)4096 * 512;

    // ---------------- stage 2 mha0: a2 only (swapped scores) ----------------
    {
        gemm_nt<E_EXPC, 128><<<dim3(32, 16, 6), 256, 0, stream>>>(
            Pk2, Pq2, Sbuf, nullptr, nullptr, rdQ,
            4096, 2048, 512, 3072, 3072, 2048, 0, sc2, 512, 512, spl2, NIL, NIL, 2048, 1, NIL, NIL);
        scale_rows_kernel<<<3072 * 2048 / 2048, 256, 0, stream>>>(VTa, VTs, rdQ, 2048, 9);
        gemm_nt<E_PART, 128><<<dim3(32, 4, 6), 256, 0, stream>>>(
            Sbuf, VTs, part, nullptr, nullptr, nullptr,
            4096, 512, 2048, 2048, 2048, 512, 0, 0.f, spl2, 512L * 2048, vpl2, NIL, NIL, NIL,
            1, NIL, NIL);
        reduce_h_elu_kernel<<<1024, 256, 0, stream>>>(part, rel_sub2, 4096, 6, nullptr);
    }
    // ---------------- stage 2 mha1: a1 only ----------------
    {
        gemm_nt<E_EXP, 128><<<dim3(32, 16, 6), 256, 0, stream>>>(
            Pk2 + (size_t)4096 * 3072, Pq2 + (size_t)2048 * 3072, Sbuf, nullptr, nullptr, rdM,
            4096, 2048, 512, 3072, 3072, 2048, 0, sc2, 512, 512, spl2, NIL, NIL, 4096, 1, NIL, NIL);
        gemm_nt<E_PART, 128><<<dim3(32, 4, 6), 256, 0, stream>>>(
            Sbuf, VTa + (size_t)3072 * 2048, part, nullptr, nullptr, nullptr,
            4096, 512, 2048, 2048, 2048, 512, 0, 0.f, spl2, 512L * 2048, vpl2, NIL, NIL, NIL,
            1, NIL, NIL);
        reduce_h_elu_kernel<<<1024, 256, 0, stream>>>(part, rel_obj2, 4096, 6, rdM);
    }

    combine_rel2_kernel<<<4096, 256, 0, stream>>>((const float4*)feat_rel, (const float4*)rel_obj2,
        (const float4*)rel_sub2, (float4*)out_rel);
}